// Round 1
// baseline (918.748 us; speedup 1.0000x reference)
//
#include <hip/hip_runtime.h>
#include <hip/hip_bf16.h>
#include <stdint.h>

#define U_NODES 50000
#define I_NODES 20000
#define N_NODES 70000
#define M_PAD   70016      // 547 * 128
#define E_EDGES 400000
#define HID     512

typedef __attribute__((ext_vector_type(8))) short short8;   // 8 bf16 (4 VGPRs)
typedef __attribute__((ext_vector_type(4))) float floatx4;  // MFMA C/D frag

static __device__ __forceinline__ uint16_t f2b(float f) {
    uint32_t x = __float_as_uint(f);
    x += 0x7fffu + ((x >> 16) & 1u);          // RNE
    return (uint16_t)(x >> 16);
}
static __device__ __forceinline__ float b2f(short u) {
    return __uint_as_float(((uint32_t)(uint16_t)u) << 16);
}

// ---------------- gather + cast embeddings to bf16 ----------------
__global__ void gather_cast(const int* __restrict__ u_gid, const int* __restrict__ i_gid,
                            const float* __restrict__ user_emb, const float* __restrict__ item_emb,
                            uint16_t* __restrict__ Xb)
{
    int t = blockIdx.x * 256 + threadIdx.x;   // over M_PAD*128 (4 elems each)
    int n = t >> 7;
    int j = (t & 127) << 2;
    uint2 o;
    if (n < N_NODES) {
        const float* src = (n < U_NODES) ? (user_emb + (size_t)u_gid[n] * HID)
                                         : (item_emb + (size_t)i_gid[n - U_NODES] * HID);
        float4 v = *(const float4*)(src + j);
        o.x = (uint32_t)f2b(v.x) | ((uint32_t)f2b(v.y) << 16);
        o.y = (uint32_t)f2b(v.z) | ((uint32_t)f2b(v.w) << 16);
    } else { o.x = 0u; o.y = 0u; }            // zero the pad rows
    *(uint2*)(Xb + (size_t)n * HID + j) = o;
}

// ---------------- W_ui|W_iu -> transposed bf16 (Wt[n][k]) ----------------
__global__ void prep_w(const float* __restrict__ Wui, const float* __restrict__ Wiu,
                       uint16_t* __restrict__ Wt)
{
    int t = blockIdx.x * 256 + threadIdx.x;   // 1024*512
    int n = t >> 9, k = t & 511;
    float v = (n < 512) ? Wui[k * 512 + n] : Wiu[k * 512 + (n - 512)];
    Wt[(size_t)n * 512 + k] = f2b(v);
}

// ---------------- bf16 GEMM: F[M_PAD,1024] = Xb[M_PAD,512] @ Wt^T ----------------
// BK=64, XOR-swizzled LDS (slot ^= row&7) with pre-swizzled global source,
// XCD-aware block swizzle, fused per-node attention logits (el/er) in epilogue.
__global__ __launch_bounds__(256) void gemm_bf16(const uint16_t* __restrict__ Xb,
                                                 const uint16_t* __restrict__ Wt,
                                                 const float* __restrict__ al_ui, const float* __restrict__ ar_ui,
                                                 const float* __restrict__ al_iu, const float* __restrict__ ar_iu,
                                                 uint16_t* __restrict__ F,
                                                 float* __restrict__ ELui, float* __restrict__ ERui,
                                                 float* __restrict__ ELiu, float* __restrict__ ERiu)
{
    __shared__ __align__(16) uint16_t As[128 * 64];  // [row][slot^ (row&7)] 16B slots
    __shared__ __align__(16) uint16_t Bs[128 * 64];
    const int tid = threadIdx.x;
    const int wave = tid >> 6, lane = tid & 63;

    // XCD-aware swizzle: 8 sibling n-blocks of one m-block land on the same XCD.
    // grid = 547*8 = 4376; hw round-robins blockIdx%8 across XCDs.
    int bid = blockIdx.x;
    int x = bid & 7, ii = bid >> 3;
    int L = x * 547 + ii;                 // bijective: x in [0,8), ii in [0,547)
    const int m0 = (L >> 3) * 128;
    const int n0 = (L & 7) * 128;
    const int wm = (wave & 1) * 64;
    const int wn = (wave >> 1) * 64;

    // staging geometry: 16 chunks of 1KB per matrix; chunk c = rows c*8..c*8+7.
    // lane -> (row = c*8 + lane>>3, lds slot = lane&7); global slot pre-swizzled.
    const int rl = lane >> 3;             // row within 8-row group (== row&7)
    const int sg8 = ((lane & 7) ^ rl) * 8;   // pre-swizzled global k-slot (shorts)
    const uint16_t* gA[4]; const uint16_t* gB[4];
    uint16_t* lA[4]; uint16_t* lB[4];
    #pragma unroll
    for (int l = 0; l < 4; ++l) {
        int c = wave * 4 + l;
        gA[l] = Xb + (size_t)(m0 + c * 8 + rl) * HID + sg8;
        gB[l] = Wt + (size_t)(n0 + c * 8 + rl) * HID + sg8;
        lA[l] = As + c * 512;
        lB[l] = Bs + c * 512;
    }

    floatx4 zero = {0.f, 0.f, 0.f, 0.f};
    floatx4 acc[4][4];
    #pragma unroll
    for (int a = 0; a < 4; ++a)
        #pragma unroll
        for (int b = 0; b < 4; ++b) acc[a][b] = zero;

    const int r = lane & 15, quad = lane >> 4;
    const int rx = r & 7;                 // == row&7 for all fragment rows

    for (int k0 = 0; k0 < HID; k0 += 64) {
        __syncthreads();
        #pragma unroll
        for (int l = 0; l < 4; ++l) {
            __builtin_amdgcn_global_load_lds((const __attribute__((address_space(1))) void*)(gA[l] + k0),
                                             (__attribute__((address_space(3))) void*)lA[l], 16, 0, 0);
            __builtin_amdgcn_global_load_lds((const __attribute__((address_space(1))) void*)(gB[l] + k0),
                                             (__attribute__((address_space(3))) void*)lB[l], 16, 0, 0);
        }
        __syncthreads();
        #pragma unroll
        for (int ks = 0; ks < 2; ++ks) {
            short8 af[4], bf[4];
            #pragma unroll
            for (int tm = 0; tm < 4; ++tm) {
                int row = wm + tm * 16 + r;
                int sl = (ks * 4 + quad) ^ rx;
                af[tm] = *(const short8*)&As[row * 64 + sl * 8];
            }
            #pragma unroll
            for (int tn = 0; tn < 4; ++tn) {
                int row = wn + tn * 16 + r;
                int sl = (ks * 4 + quad) ^ rx;
                bf[tn] = *(const short8*)&Bs[row * 64 + sl * 8];
            }
            #pragma unroll
            for (int tm = 0; tm < 4; ++tm)
                #pragma unroll
                for (int tn = 0; tn < 4; ++tn)
                    acc[tm][tn] = __builtin_amdgcn_mfma_f32_16x16x32_bf16(af[tm], bf[tn], acc[tm][tn], 0, 0, 0);
        }
    }

    // ---- C store. C/D layout: col = lane&15, row = quad*4 + reg ----
    #pragma unroll
    for (int tm = 0; tm < 4; ++tm) {
        #pragma unroll
        for (int rr = 0; rr < 4; ++rr) {
            int row = m0 + wm + tm * 16 + quad * 4 + rr;
            if (row < N_NODES) {
                #pragma unroll
                for (int tn = 0; tn < 4; ++tn) {
                    int col = n0 + wn + tn * 16 + r;
                    F[(size_t)row * 1024 + col] = f2b(acc[tm][tn][rr]);
                }
            }
        }
    }

    // ---- fused attention logits: this wave's 64 cols == exactly one head ----
    int colh = n0 + wn;                   // multiple of 64
    bool is_ui = colh < 512;
    int h = (colh & 511) >> 6;
    const float* alv = is_ui ? al_ui : al_iu;
    const float* arv = is_ui ? ar_ui : ar_iu;
    float* ELp = is_ui ? ELui : ELiu;
    float* ERp = is_ui ? ERui : ERiu;
    float al4[4], ar4[4];
    #pragma unroll
    for (int tn = 0; tn < 4; ++tn) {
        al4[tn] = alv[h * 64 + tn * 16 + r];
        ar4[tn] = arv[h * 64 + tn * 16 + r];
    }
    #pragma unroll
    for (int tm = 0; tm < 4; ++tm) {
        #pragma unroll
        for (int rr = 0; rr < 4; ++rr) {
            float sl = 0.f, sr = 0.f;
            #pragma unroll
            for (int tn = 0; tn < 4; ++tn) {
                sl += acc[tm][tn][rr] * al4[tn];
                sr += acc[tm][tn][rr] * ar4[tn];
            }
            #pragma unroll
            for (int d = 1; d < 16; d <<= 1) {   // reduce across the 16 col-lanes
                sl += __shfl_xor(sl, d);
                sr += __shfl_xor(sr, d);
            }
            if (r == 0) {
                int row = m0 + wm + tm * 16 + quad * 4 + rr;
                if (row < N_NODES) {
                    ELp[row * 8 + h] = sl;
                    ERp[row * 8 + h] = sr;
                }
            }
        }
    }
}

// ---------------- CSR build ----------------
__global__ void hist_kernel(const int* __restrict__ src_u, const int* __restrict__ dst_i,
                            int* __restrict__ counts_i, int* __restrict__ counts_u)
{
    int e = blockIdx.x * 256 + threadIdx.x;
    if (e >= E_EDGES) return;
    atomicAdd(&counts_i[dst_i[e]], 1);
    atomicAdd(&counts_u[src_u[e]], 1);
}

__global__ __launch_bounds__(1024) void scan_kernel(const int* __restrict__ counts_i,
                                                    const int* __restrict__ counts_u,
                                                    int* __restrict__ offs_i, int* __restrict__ cur_i,
                                                    int* __restrict__ offs_u, int* __restrict__ cur_u)
{
    const int* counts; int n; int* offs; int* cur;
    if (blockIdx.x == 0) { counts = counts_i; n = I_NODES; offs = offs_i; cur = cur_i; }
    else                 { counts = counts_u; n = U_NODES; offs = offs_u; cur = cur_u; }
    __shared__ int wsum[16];
    int tid = threadIdx.x, lane = tid & 63, w = tid >> 6;
    int carry = 0;
    for (int base = 0; base < n; base += 1024) {
        int i = base + tid;
        int v = (i < n) ? counts[i] : 0;
        int x = v;
        #pragma unroll
        for (int d = 1; d < 64; d <<= 1) {
            int y = __shfl_up(x, d, 64);
            if (lane >= d) x += y;
        }
        if (lane == 63) wsum[w] = x;
        __syncthreads();
        if (w == 0) {
            int s = (lane < 16) ? wsum[lane] : 0;
            #pragma unroll
            for (int d = 1; d < 16; d <<= 1) {
                int y = __shfl_up(s, d, 16);
                if ((lane & 15) >= d) s += y;
            }
            if (lane < 16) wsum[lane] = s;    // inclusive per-wave sums
        }
        __syncthreads();
        int wexcl = (w == 0) ? 0 : wsum[w - 1];
        int excl = carry + wexcl + (x - v);
        if (i < n) { offs[i] = excl; cur[i] = excl; }
        int tot = wsum[15];
        __syncthreads();
        carry += tot;
    }
    if (tid == 0) offs[n] = carry;
}

// scatter + per-edge attention weights exp(leaky(el+er)) for both directions
__global__ void scatter_kernel(const int* __restrict__ src_u, const int* __restrict__ dst_i,
                               int* __restrict__ cur_i, int* __restrict__ cur_u,
                               int* __restrict__ sorted_ui, int* __restrict__ sorted_iu,
                               const float* __restrict__ ELui, const float* __restrict__ ERui,
                               const float* __restrict__ ELiu, const float* __restrict__ ERiu,
                               float* __restrict__ ex_ui, float* __restrict__ ex_iu)
{
    int e = blockIdx.x * 256 + threadIdx.x;
    if (e >= E_EDGES) return;
    int s = src_u[e], d = dst_i[e];
    int dn = U_NODES + d;
    int p = atomicAdd(&cur_i[d], 1);
    int q = atomicAdd(&cur_u[s], 1);
    sorted_ui[p] = s;                  // user node id (src for ui)
    sorted_iu[q] = dn;                 // item node id (src for iu)
    #pragma unroll
    for (int h = 0; h < 8; ++h) {
        float e1 = ELui[s * 8 + h] + ERui[dn * 8 + h];     // user -> item
        e1 = (e1 >= 0.f) ? e1 : 0.2f * e1;
        ex_ui[(size_t)p * 8 + h] = __expf(e1);
        float e2 = ELiu[dn * 8 + h] + ERiu[s * 8 + h];     // item -> user
        e2 = (e2 >= 0.f) ? e2 : 0.2f * e2;
        ex_iu[(size_t)q * 8 + h] = __expf(e2);
    }
}

// ---------------- unified per-destination softmax + aggregate (single pass) ----------------
// wave per dst; grid covers item-dsts then user-dsts. No atomics: item rows
// stream to itemF and are tree-reduced afterwards.
#define IBLK ((I_NODES + 3) / 4)
#define UBLK ((U_NODES + 3) / 4)
__global__ __launch_bounds__(256) void agg3_kernel(
    const int* __restrict__ offs_i, const int* __restrict__ sorted_ui, const float* __restrict__ ex_ui,
    const int* __restrict__ offs_u, const int* __restrict__ sorted_iu, const float* __restrict__ ex_iu,
    const uint16_t* __restrict__ F, const float* __restrict__ b_iu,
    float* __restrict__ out, float* __restrict__ itemF)
{
    int bid = blockIdx.x;
    int w = threadIdx.x >> 6, lane = threadIdx.x & 63;
    bool item_mode = bid < IBLK;
    const int* offs; const int* srcs; const float* ex; int dst, colbase, n_dst;
    if (item_mode) { offs = offs_i; srcs = sorted_ui; ex = ex_ui; dst = bid * 4 + w;          colbase = 0;   n_dst = I_NODES; }
    else           { offs = offs_u; srcs = sorted_iu; ex = ex_iu; dst = (bid - IBLK) * 4 + w; colbase = 512; n_dst = U_NODES; }
    if (dst >= n_dst) return;
    int h = lane >> 3;
    int j0 = offs[dst], j1 = offs[dst + 1];

    // single pass: accumulate unnormalized sum and denominator together.
    // all 8 lanes of head h load the same ex value -> den is free per lane.
    float den = 0.f;
    float acc[8] = {0.f, 0.f, 0.f, 0.f, 0.f, 0.f, 0.f, 0.f};
    const int fb = colbase + lane * 8;
    int j = j0;
    for (; j + 8 <= j1; j += 8) {
        int s[8]; float wt[8]; short8 f[8];
        #pragma unroll
        for (int i = 0; i < 8; ++i) s[i] = srcs[j + i];
        #pragma unroll
        for (int i = 0; i < 8; ++i) wt[i] = ex[(size_t)(j + i) * 8 + h];
        #pragma unroll
        for (int i = 0; i < 8; ++i) f[i] = *(const short8*)&F[(size_t)s[i] * 1024 + fb];
        #pragma unroll
        for (int i = 0; i < 8; ++i) {
            den += wt[i];
            #pragma unroll
            for (int q = 0; q < 8; ++q) acc[q] += wt[i] * b2f(f[i][q]);
        }
    }
    for (; j + 4 <= j1; j += 4) {
        int s[4]; float wt[4]; short8 f[4];
        #pragma unroll
        for (int i = 0; i < 4; ++i) s[i] = srcs[j + i];
        #pragma unroll
        for (int i = 0; i < 4; ++i) wt[i] = ex[(size_t)(j + i) * 8 + h];
        #pragma unroll
        for (int i = 0; i < 4; ++i) f[i] = *(const short8*)&F[(size_t)s[i] * 1024 + fb];
        #pragma unroll
        for (int i = 0; i < 4; ++i) {
            den += wt[i];
            #pragma unroll
            for (int q = 0; q < 8; ++q) acc[q] += wt[i] * b2f(f[i][q]);
        }
    }
    for (; j < j1; ++j) {
        int s0 = srcs[j];
        float w0 = ex[(size_t)j * 8 + h];
        short8 f0 = *(const short8*)&F[(size_t)s0 * 1024 + fb];
        den += w0;
        #pragma unroll
        for (int q = 0; q < 8; ++q) acc[q] += w0 * b2f(f0[q]);
    }
    float inv = (j1 > j0) ? (1.f / den) : 0.f;
    #pragma unroll
    for (int q = 0; q < 8; ++q) acc[q] *= inv;

    int col = lane * 8;
    if (item_mode) {
        float* o = itemF + (size_t)dst * 512 + col;       // bias folded in later
        float4 v0 = {acc[0], acc[1], acc[2], acc[3]};
        float4 v1 = {acc[4], acc[5], acc[6], acc[7]};
        *(float4*)(o + 0) = v0;
        *(float4*)(o + 4) = v1;
    } else {
        float* o = out + (size_t)dst * 1024 + col;
        float4 v0 = {acc[0] + b_iu[col + 0], acc[1] + b_iu[col + 1],
                     acc[2] + b_iu[col + 2], acc[3] + b_iu[col + 3]};
        float4 v1 = {acc[4] + b_iu[col + 4], acc[5] + b_iu[col + 5],
                     acc[6] + b_iu[col + 6], acc[7] + b_iu[col + 7]};
        *(float4*)(o + 0) = v0;
        *(float4*)(o + 4) = v1;
    }
}

// ---------------- item mean: tree reduce itemF[20000][512] ----------------
// 40 blocks x 500 rows; block writes 2 partial stripes (rows split by t>>7)
__global__ void item_reduce(const float* __restrict__ itemF, float* __restrict__ partial2)
{
    int b = blockIdx.x;             // 0..39
    int t = threadIdx.x;            // 256
    int cg = (t & 127) * 4;         // column group (float4)
    int rp = t >> 7;                // 0/1
    float4 s = {0.f, 0.f, 0.f, 0.f};
    int r0 = b * 500;
    for (int r = r0 + rp; r < r0 + 500; r += 2) {
        float4 v = *(const float4*)&itemF[(size_t)r * 512 + cg];
        s.x += v.x; s.y += v.y; s.z += v.z; s.w += v.w;
    }
    *(float4*)&partial2[(size_t)(b * 2 + rp) * 512 + cg] = s;
}

__global__ void meanvec_kernel(const float* __restrict__ partial2, const float* __restrict__ b_ui,
                               float* __restrict__ mean_vec)
{
    int c = threadIdx.x;   // 512
    float s = 0.f;
    for (int p = 0; p < 80; ++p) s += partial2[p * 512 + c];
    mean_vec[c] = s * (1.0f / (float)I_NODES) + b_ui[c];
}

__global__ void bcast_kernel(const float* __restrict__ mean_vec, float* __restrict__ out)
{
    int t = blockIdx.x * 256 + threadIdx.x;   // U*128
    int u = t >> 7, q = t & 127;
    float4 v = ((const float4*)mean_vec)[q];
    *(float4*)(out + (size_t)u * 1024 + 512 + q * 4) = v;
}

extern "C" void kernel_launch(void* const* d_in, const int* in_sizes, int n_in,
                              void* d_out, int out_size, void* d_ws, size_t ws_size,
                              hipStream_t stream)
{
    const int*   u_gid    = (const int*)d_in[0];
    const int*   i_gid    = (const int*)d_in[1];
    const int*   src_u    = (const int*)d_in[2];
    const int*   dst_i    = (const int*)d_in[3];
    const float* user_emb = (const float*)d_in[4];
    const float* item_emb = (const float*)d_in[5];
    const float* W_ui     = (const float*)d_in[6];
    const float* al_ui    = (const float*)d_in[7];
    const float* ar_ui    = (const float*)d_in[8];
    const float* b_ui     = (const float*)d_in[9];
    const float* W_iu     = (const float*)d_in[10];
    const float* al_iu    = (const float*)d_in[11];
    const float* ar_iu    = (const float*)d_in[12];
    const float* b_iu     = (const float*)d_in[13];
    float* out = (float*)d_out;

    char* ws = (char*)d_ws;
    size_t off = 0;
    auto alloc = [&](size_t bytes) -> void* {
        void* p = ws + off;
        off = (off + bytes + 255) & ~(size_t)255;
        return p;
    };
    uint16_t* Xb   = (uint16_t*)alloc((size_t)M_PAD * 512 * 2);
    uint16_t* Wt   = (uint16_t*)alloc((size_t)1024 * 512 * 2);
    uint16_t* F    = (uint16_t*)alloc((size_t)M_PAD * 1024 * 2);
    float* ELui    = (float*)alloc((size_t)N_NODES * 8 * 4);
    float* ERui    = (float*)alloc((size_t)N_NODES * 8 * 4);
    float* ELiu    = (float*)alloc((size_t)N_NODES * 8 * 4);
    float* ERiu    = (float*)alloc((size_t)N_NODES * 8 * 4);
    int* offs_i    = (int*)alloc((size_t)(I_NODES + 1) * 4);
    int* cur_i     = (int*)alloc((size_t)I_NODES * 4);
    int* offs_u    = (int*)alloc((size_t)(U_NODES + 1) * 4);
    int* cur_u     = (int*)alloc((size_t)U_NODES * 4);
    int* sorted_ui = (int*)alloc((size_t)E_EDGES * 4);
    int* sorted_iu = (int*)alloc((size_t)E_EDGES * 4);
    float* ex_ui   = (float*)alloc((size_t)E_EDGES * 8 * 4);
    float* ex_iu   = (float*)alloc((size_t)E_EDGES * 8 * 4);
    float* itemF   = (float*)alloc((size_t)I_NODES * 512 * 4);
    float* partial2= (float*)alloc((size_t)80 * 512 * 4);
    // zeroed region (contiguous): counts_i, counts_u
    char* zptr = ws + off;
    int*   counts_i = (int*)alloc((size_t)I_NODES * 4);
    int*   counts_u = (int*)alloc((size_t)U_NODES * 4);
    size_t zbytes = (size_t)((ws + off) - zptr);
    float* mean_vec = (float*)alloc(512 * 4);
    (void)ws_size; (void)in_sizes; (void)n_in; (void)out_size;

    hipMemsetAsync(zptr, 0, zbytes, stream);
    prep_w<<<2048, 256, 0, stream>>>(W_ui, W_iu, Wt);
    gather_cast<<<M_PAD * 128 / 256, 256, 0, stream>>>(u_gid, i_gid, user_emb, item_emb, Xb);
    gemm_bf16<<<(M_PAD / 128) * 8, 256, 0, stream>>>(Xb, Wt, al_ui, ar_ui, al_iu, ar_iu,
                                                     F, ELui, ERui, ELiu, ERiu);
    hist_kernel<<<(E_EDGES + 255) / 256, 256, 0, stream>>>(src_u, dst_i, counts_i, counts_u);
    scan_kernel<<<2, 1024, 0, stream>>>(counts_i, counts_u, offs_i, cur_i, offs_u, cur_u);
    scatter_kernel<<<(E_EDGES + 255) / 256, 256, 0, stream>>>(src_u, dst_i, cur_i, cur_u,
                                                              sorted_ui, sorted_iu,
                                                              ELui, ERui, ELiu, ERiu,
                                                              ex_ui, ex_iu);
    agg3_kernel<<<IBLK + UBLK, 256, 0, stream>>>(offs_i, sorted_ui, ex_ui,
                                                 offs_u, sorted_iu, ex_iu,
                                                 F, b_iu, out, itemF);
    item_reduce<<<40, 256, 0, stream>>>(itemF, partial2);
    meanvec_kernel<<<1, 512, 0, stream>>>(partial2, b_ui, mean_vec);
    bcast_kernel<<<U_NODES * 128 / 256, 256, 0, stream>>>(mean_vec, out);
}

// Round 3
// 880.083 us; speedup vs baseline: 1.0439x; 1.0439x over previous
//
#include <hip/hip_runtime.h>
#include <hip/hip_bf16.h>
#include <stdint.h>

#define U_NODES 50000
#define I_NODES 20000
#define N_NODES 70000
#define M_PAD   70016      // 547 * 128
#define E_EDGES 400000
#define HID     512

typedef __attribute__((ext_vector_type(8))) short short8;   // 8 bf16 (4 VGPRs)
typedef __attribute__((ext_vector_type(4))) float floatx4;  // MFMA C/D frag

static __device__ __forceinline__ uint16_t f2b(float f) {
    uint32_t x = __float_as_uint(f);
    x += 0x7fffu + ((x >> 16) & 1u);          // RNE
    return (uint16_t)(x >> 16);
}
static __device__ __forceinline__ float b2f(short u) {
    return __uint_as_float(((uint32_t)(uint16_t)u) << 16);
}

// ---------------- gather + cast embeddings to bf16 ----------------
__global__ void gather_cast(const int* __restrict__ u_gid, const int* __restrict__ i_gid,
                            const float* __restrict__ user_emb, const float* __restrict__ item_emb,
                            uint16_t* __restrict__ Xb)
{
    int t = blockIdx.x * 256 + threadIdx.x;   // over M_PAD*128 (4 elems each)
    int n = t >> 7;
    int j = (t & 127) << 2;
    uint2 o;
    if (n < N_NODES) {
        const float* src = (n < U_NODES) ? (user_emb + (size_t)u_gid[n] * HID)
                                         : (item_emb + (size_t)i_gid[n - U_NODES] * HID);
        float4 v = *(const float4*)(src + j);
        o.x = (uint32_t)f2b(v.x) | ((uint32_t)f2b(v.y) << 16);
        o.y = (uint32_t)f2b(v.z) | ((uint32_t)f2b(v.w) << 16);
    } else { o.x = 0u; o.y = 0u; }            // zero the pad rows
    *(uint2*)(Xb + (size_t)n * HID + j) = o;
}

// ---------------- W_ui|W_iu -> transposed bf16 (Wt[n][k]) ----------------
__global__ void prep_w(const float* __restrict__ Wui, const float* __restrict__ Wiu,
                       uint16_t* __restrict__ Wt)
{
    int t = blockIdx.x * 256 + threadIdx.x;   // 1024*512
    int n = t >> 9, k = t & 511;
    float v = (n < 512) ? Wui[k * 512 + n] : Wiu[k * 512 + (n - 512)];
    Wt[(size_t)n * 512 + k] = f2b(v);
}

// ---------------- bf16 GEMM: F[M_PAD,1024] = Xb[M_PAD,512] @ Wt^T ----------------
// BK=32, double-buffered LDS, 2-phase pipeline (stage t+1 before compute t),
// XOR swizzle slot^=(row>>1)&3 (conflict-free b128 reads, linear gload_lds dest),
// XCD-aware block swizzle, fused EL/ER epilogue, dead-half F stores skipped.
__global__ __launch_bounds__(256) void gemm_bf16(const uint16_t* __restrict__ Xb,
                                                 const uint16_t* __restrict__ Wt,
                                                 const float* __restrict__ al_ui, const float* __restrict__ ar_ui,
                                                 const float* __restrict__ al_iu, const float* __restrict__ ar_iu,
                                                 uint16_t* __restrict__ F,
                                                 float* __restrict__ ELui, float* __restrict__ ERui,
                                                 float* __restrict__ ELiu, float* __restrict__ ERiu)
{
    __shared__ __align__(16) uint16_t As[2][128 * 32];
    __shared__ __align__(16) uint16_t Bs[2][128 * 32];
    const int tid = threadIdx.x;
    const int wave = tid >> 6, lane = tid & 63;

    // XCD-aware swizzle: 8 sibling n-blocks of one m-block land on the same XCD.
    int bid = blockIdx.x;
    int x = bid & 7, ii = bid >> 3;
    int L = x * 547 + ii;                 // bijective: grid 4376 = 8*547
    const int m0 = (L >> 3) * 128;
    const int n0 = (L & 7) * 128;
    const int wm = (wave & 1) * 64;
    const int wn = (wave >> 1) * 64;

    // staging: tile 128x32 = 8 chunks of 1KB; wave stages 2 A-chunks + 2 B-chunks.
    // lane -> row = c*16 + (lane>>2); global k-slot pre-swizzled by (lane>>3)&3.
    const int rl2 = lane >> 2;
    const int sg = ((lane & 3) ^ ((lane >> 3) & 3)) * 8;   // shorts
    const int ca = wave * 2, cb = wave * 2 + 1;
    const uint16_t* gA0 = Xb + (size_t)(m0 + ca * 16 + rl2) * HID + sg;
    const uint16_t* gA1 = Xb + (size_t)(m0 + cb * 16 + rl2) * HID + sg;
    const uint16_t* gB0 = Wt + (size_t)(n0 + ca * 16 + rl2) * HID + sg;
    const uint16_t* gB1 = Wt + (size_t)(n0 + cb * 16 + rl2) * HID + sg;

    floatx4 zero = {0.f, 0.f, 0.f, 0.f};
    floatx4 acc[4][4];
    #pragma unroll
    for (int a = 0; a < 4; ++a)
        #pragma unroll
        for (int b = 0; b < 4; ++b) acc[a][b] = zero;

    const int r = lane & 15, quad = lane >> 4;
    const int slq8 = (quad ^ ((r >> 1) & 3)) * 8;   // swizzled 8-short slot for reads

#define STAGE(KO, BUF) do {                                                                         \
    __builtin_amdgcn_global_load_lds((const __attribute__((address_space(1))) void*)(gA0 + (KO)),   \
                                     (__attribute__((address_space(3))) void*)(&As[BUF][ca * 512]), 16, 0, 0); \
    __builtin_amdgcn_global_load_lds((const __attribute__((address_space(1))) void*)(gA1 + (KO)),   \
                                     (__attribute__((address_space(3))) void*)(&As[BUF][cb * 512]), 16, 0, 0); \
    __builtin_amdgcn_global_load_lds((const __attribute__((address_space(1))) void*)(gB0 + (KO)),   \
                                     (__attribute__((address_space(3))) void*)(&Bs[BUF][ca * 512]), 16, 0, 0); \
    __builtin_amdgcn_global_load_lds((const __attribute__((address_space(1))) void*)(gB1 + (KO)),   \
                                     (__attribute__((address_space(3))) void*)(&Bs[BUF][cb * 512]), 16, 0, 0); \
} while (0)

#define COMPUTE(BUF) do {                                                                           \
    short8 af[4], bf[4];                                                                            \
    _Pragma("unroll")                                                                               \
    for (int tm = 0; tm < 4; ++tm)                                                                  \
        af[tm] = *(const short8*)&As[BUF][(wm + tm * 16 + r) * 32 + slq8];                          \
    _Pragma("unroll")                                                                               \
    for (int tn = 0; tn < 4; ++tn)                                                                  \
        bf[tn] = *(const short8*)&Bs[BUF][(wn + tn * 16 + r) * 32 + slq8];                          \
    _Pragma("unroll")                                                                               \
    for (int tm = 0; tm < 4; ++tm)                                                                  \
        _Pragma("unroll")                                                                           \
        for (int tn = 0; tn < 4; ++tn)                                                              \
            acc[tm][tn] = __builtin_amdgcn_mfma_f32_16x16x32_bf16(af[tm], bf[tn], acc[tm][tn], 0, 0, 0); \
} while (0)

    // prologue: tile 0 -> buf 0
    STAGE(0, 0);
    __syncthreads();
    // 2-phase pipeline: stage t+1 into buf^1, compute tile t, one barrier/step.
    #pragma unroll
    for (int t = 0; t < 15; ++t) {
        const int bc = t & 1;
        STAGE((t + 1) * 32, bc ^ 1);
        COMPUTE(bc);
        __syncthreads();
    }
    COMPUTE(1);

#undef STAGE
#undef COMPUTE

    // ---- epilogue ----
    // col-half of this block and row-half of this m-panel decide which F stores
    // are live: agg3 reads only F[user][0:512] and F[item][512:1024].
    const bool collo = (n0 < 512);
    const bool allU = (m0 + 128 <= U_NODES);
    const bool allI = (m0 >= U_NODES);
    const bool storeb = (allU && collo) || (allI && !collo) || (!allU && !allI);

    const int colh = n0 + wn;                 // multiple of 64 -> exactly one head
    const int h = (colh & 511) >> 6;
    const float* arv = collo ? ar_ui : ar_iu;
    float* ERp = collo ? ERui : ERiu;
    float ar4[4];
    #pragma unroll
    for (int tn = 0; tn < 4; ++tn) ar4[tn] = arv[h * 64 + tn * 16 + r];

    if (storeb) {
        const float* alv = collo ? al_ui : al_iu;
        float* ELp = collo ? ELui : ELiu;
        float al4[4];
        #pragma unroll
        for (int tn = 0; tn < 4; ++tn) al4[tn] = alv[h * 64 + tn * 16 + r];
        #pragma unroll
        for (int tm = 0; tm < 4; ++tm) {
            #pragma unroll
            for (int rr = 0; rr < 4; ++rr) {
                int row = m0 + wm + tm * 16 + quad * 4 + rr;
                float sl = 0.f, sr = 0.f;
                #pragma unroll
                for (int tn = 0; tn < 4; ++tn) {
                    sl += acc[tm][tn][rr] * al4[tn];
                    sr += acc[tm][tn][rr] * ar4[tn];
                }
                if (row < N_NODES && ((row < U_NODES) == collo)) {
                    #pragma unroll
                    for (int tn = 0; tn < 4; ++tn) {
                        int col = n0 + wn + tn * 16 + r;
                        F[(size_t)row * 1024 + col] = f2b(acc[tm][tn][rr]);
                    }
                }
                #pragma unroll
                for (int d = 1; d < 16; d <<= 1) {
                    sl += __shfl_xor(sl, d);
                    sr += __shfl_xor(sr, d);
                }
                if (r == 0 && row < N_NODES) {
                    ELp[row * 8 + h] = sl;
                    ERp[row * 8 + h] = sr;
                }
            }
        }
    } else {
        // wrong-half block: F stores dead, only ER needed (dst-side logits).
        #pragma unroll
        for (int tm = 0; tm < 4; ++tm) {
            #pragma unroll
            for (int rr = 0; rr < 4; ++rr) {
                int row = m0 + wm + tm * 16 + quad * 4 + rr;
                float sr = 0.f;
                #pragma unroll
                for (int tn = 0; tn < 4; ++tn) sr += acc[tm][tn][rr] * ar4[tn];
                #pragma unroll
                for (int d = 1; d < 16; d <<= 1) sr += __shfl_xor(sr, d);
                if (r == 0 && row < N_NODES) ERp[row * 8 + h] = sr;
            }
        }
    }
}

// ---------------- CSR build ----------------
__global__ void hist_kernel(const int* __restrict__ src_u, const int* __restrict__ dst_i,
                            int* __restrict__ counts_i, int* __restrict__ counts_u)
{
    int e = blockIdx.x * 256 + threadIdx.x;
    if (e >= E_EDGES) return;
    atomicAdd(&counts_i[dst_i[e]], 1);
    atomicAdd(&counts_u[src_u[e]], 1);
}

__global__ __launch_bounds__(1024) void scan_kernel(const int* __restrict__ counts_i,
                                                    const int* __restrict__ counts_u,
                                                    int* __restrict__ offs_i, int* __restrict__ cur_i,
                                                    int* __restrict__ offs_u, int* __restrict__ cur_u)
{
    const int* counts; int n; int* offs; int* cur;
    if (blockIdx.x == 0) { counts = counts_i; n = I_NODES; offs = offs_i; cur = cur_i; }
    else                 { counts = counts_u; n = U_NODES; offs = offs_u; cur = cur_u; }
    __shared__ int wsum[16];
    int tid = threadIdx.x, lane = tid & 63, w = tid >> 6;
    int carry = 0;
    for (int base = 0; base < n; base += 1024) {
        int i = base + tid;
        int v = (i < n) ? counts[i] : 0;
        int x = v;
        #pragma unroll
        for (int d = 1; d < 64; d <<= 1) {
            int y = __shfl_up(x, d, 64);
            if (lane >= d) x += y;
        }
        if (lane == 63) wsum[w] = x;
        __syncthreads();
        if (w == 0) {
            int s = (lane < 16) ? wsum[lane] : 0;
            #pragma unroll
            for (int d = 1; d < 16; d <<= 1) {
                int y = __shfl_up(s, d, 16);
                if ((lane & 15) >= d) s += y;
            }
            if (lane < 16) wsum[lane] = s;    // inclusive per-wave sums
        }
        __syncthreads();
        int wexcl = (w == 0) ? 0 : wsum[w - 1];
        int excl = carry + wexcl + (x - v);
        if (i < n) { offs[i] = excl; cur[i] = excl; }
        int tot = wsum[15];
        __syncthreads();
        carry += tot;
    }
    if (tid == 0) offs[n] = carry;
}

// scatter + per-edge attention weights exp(leaky(el+er)) for both directions
__global__ void scatter_kernel(const int* __restrict__ src_u, const int* __restrict__ dst_i,
                               int* __restrict__ cur_i, int* __restrict__ cur_u,
                               int* __restrict__ sorted_ui, int* __restrict__ sorted_iu,
                               const float* __restrict__ ELui, const float* __restrict__ ERui,
                               const float* __restrict__ ELiu, const float* __restrict__ ERiu,
                               float* __restrict__ ex_ui, float* __restrict__ ex_iu)
{
    int e = blockIdx.x * 256 + threadIdx.x;
    if (e >= E_EDGES) return;
    int s = src_u[e], d = dst_i[e];
    int dn = U_NODES + d;
    int p = atomicAdd(&cur_i[d], 1);
    int q = atomicAdd(&cur_u[s], 1);
    sorted_ui[p] = s;                  // user node id (src for ui)
    sorted_iu[q] = dn;                 // item node id (src for iu)
    #pragma unroll
    for (int h = 0; h < 8; ++h) {
        float e1 = ELui[s * 8 + h] + ERui[dn * 8 + h];     // user -> item
        e1 = (e1 >= 0.f) ? e1 : 0.2f * e1;
        ex_ui[(size_t)p * 8 + h] = __expf(e1);
        float e2 = ELiu[dn * 8 + h] + ERiu[s * 8 + h];     // item -> user
        e2 = (e2 >= 0.f) ? e2 : 0.2f * e2;
        ex_iu[(size_t)q * 8 + h] = __expf(e2);
    }
}

// ---------------- unified per-destination softmax + aggregate (single pass) ----------------
#define IBLK ((I_NODES + 3) / 4)
#define UBLK ((U_NODES + 3) / 4)
__global__ __launch_bounds__(256) void agg3_kernel(
    const int* __restrict__ offs_i, const int* __restrict__ sorted_ui, const float* __restrict__ ex_ui,
    const int* __restrict__ offs_u, const int* __restrict__ sorted_iu, const float* __restrict__ ex_iu,
    const uint16_t* __restrict__ F, const float* __restrict__ b_iu,
    float* __restrict__ out, float* __restrict__ itemF)
{
    int bid = blockIdx.x;
    int w = threadIdx.x >> 6, lane = threadIdx.x & 63;
    bool item_mode = bid < IBLK;
    const int* offs; const int* srcs; const float* ex; int dst, colbase, n_dst;
    if (item_mode) { offs = offs_i; srcs = sorted_ui; ex = ex_ui; dst = bid * 4 + w;          colbase = 0;   n_dst = I_NODES; }
    else           { offs = offs_u; srcs = sorted_iu; ex = ex_iu; dst = (bid - IBLK) * 4 + w; colbase = 512; n_dst = U_NODES; }
    if (dst >= n_dst) return;
    int h = lane >> 3;
    int j0 = offs[dst], j1 = offs[dst + 1];

    float den = 0.f;
    float acc[8] = {0.f, 0.f, 0.f, 0.f, 0.f, 0.f, 0.f, 0.f};
    const int fb = colbase + lane * 8;
    int j = j0;
    for (; j + 8 <= j1; j += 8) {
        int s[8]; float wt[8]; short8 f[8];
        #pragma unroll
        for (int i = 0; i < 8; ++i) s[i] = srcs[j + i];
        #pragma unroll
        for (int i = 0; i < 8; ++i) wt[i] = ex[(size_t)(j + i) * 8 + h];
        #pragma unroll
        for (int i = 0; i < 8; ++i) f[i] = *(const short8*)&F[(size_t)s[i] * 1024 + fb];
        #pragma unroll
        for (int i = 0; i < 8; ++i) {
            den += wt[i];
            #pragma unroll
            for (int q = 0; q < 8; ++q) acc[q] += wt[i] * b2f(f[i][q]);
        }
    }
    for (; j + 4 <= j1; j += 4) {
        int s[4]; float wt[4]; short8 f[4];
        #pragma unroll
        for (int i = 0; i < 4; ++i) s[i] = srcs[j + i];
        #pragma unroll
        for (int i = 0; i < 4; ++i) wt[i] = ex[(size_t)(j + i) * 8 + h];
        #pragma unroll
        for (int i = 0; i < 4; ++i) f[i] = *(const short8*)&F[(size_t)s[i] * 1024 + fb];
        #pragma unroll
        for (int i = 0; i < 4; ++i) {
            den += wt[i];
            #pragma unroll
            for (int q = 0; q < 8; ++q) acc[q] += wt[i] * b2f(f[i][q]);
        }
    }
    for (; j < j1; ++j) {
        int s0 = srcs[j];
        float w0 = ex[(size_t)j * 8 + h];
        short8 f0 = *(const short8*)&F[(size_t)s0 * 1024 + fb];
        den += w0;
        #pragma unroll
        for (int q = 0; q < 8; ++q) acc[q] += w0 * b2f(f0[q]);
    }
    float inv = (j1 > j0) ? (1.f / den) : 0.f;
    #pragma unroll
    for (int q = 0; q < 8; ++q) acc[q] *= inv;

    int col = lane * 8;
    if (item_mode) {
        float* o = itemF + (size_t)dst * 512 + col;       // bias folded in later
        float4 v0 = {acc[0], acc[1], acc[2], acc[3]};
        float4 v1 = {acc[4], acc[5], acc[6], acc[7]};
        *(float4*)(o + 0) = v0;
        *(float4*)(o + 4) = v1;
    } else {
        float* o = out + (size_t)dst * 1024 + col;
        float4 v0 = {acc[0] + b_iu[col + 0], acc[1] + b_iu[col + 1],
                     acc[2] + b_iu[col + 2], acc[3] + b_iu[col + 3]};
        float4 v1 = {acc[4] + b_iu[col + 4], acc[5] + b_iu[col + 5],
                     acc[6] + b_iu[col + 6], acc[7] + b_iu[col + 7]};
        *(float4*)(o + 0) = v0;
        *(float4*)(o + 4) = v1;
    }
}

// ---------------- item mean: tree reduce itemF[20000][512] ----------------
__global__ void item_reduce(const float* __restrict__ itemF, float* __restrict__ partial2)
{
    int b = blockIdx.x;             // 0..39
    int t = threadIdx.x;            // 256
    int cg = (t & 127) * 4;         // column group (float4)
    int rp = t >> 7;                // 0/1
    float4 s = {0.f, 0.f, 0.f, 0.f};
    int r0 = b * 500;
    for (int r = r0 + rp; r < r0 + 500; r += 2) {
        float4 v = *(const float4*)&itemF[(size_t)r * 512 + cg];
        s.x += v.x; s.y += v.y; s.z += v.z; s.w += v.w;
    }
    *(float4*)&partial2[(size_t)(b * 2 + rp) * 512 + cg] = s;
}

__global__ void meanvec_kernel(const float* __restrict__ partial2, const float* __restrict__ b_ui,
                               float* __restrict__ mean_vec)
{
    int c = threadIdx.x;   // 512
    float s = 0.f;
    for (int p = 0; p < 80; ++p) s += partial2[p * 512 + c];
    mean_vec[c] = s * (1.0f / (float)I_NODES) + b_ui[c];
}

__global__ void bcast_kernel(const float* __restrict__ mean_vec, float* __restrict__ out)
{
    int t = blockIdx.x * 256 + threadIdx.x;   // U*128
    int u = t >> 7, q = t & 127;
    float4 v = ((const float4*)mean_vec)[q];
    *(float4*)(out + (size_t)u * 1024 + 512 + q * 4) = v;
}

extern "C" void kernel_launch(void* const* d_in, const int* in_sizes, int n_in,
                              void* d_out, int out_size, void* d_ws, size_t ws_size,
                              hipStream_t stream)
{
    const int*   u_gid    = (const int*)d_in[0];
    const int*   i_gid    = (const int*)d_in[1];
    const int*   src_u    = (const int*)d_in[2];
    const int*   dst_i    = (const int*)d_in[3];
    const float* user_emb = (const float*)d_in[4];
    const float* item_emb = (const float*)d_in[5];
    const float* W_ui     = (const float*)d_in[6];
    const float* al_ui    = (const float*)d_in[7];
    const float* ar_ui    = (const float*)d_in[8];
    const float* b_ui     = (const float*)d_in[9];
    const float* W_iu     = (const float*)d_in[10];
    const float* al_iu    = (const float*)d_in[11];
    const float* ar_iu    = (const float*)d_in[12];
    const float* b_iu     = (const float*)d_in[13];
    float* out = (float*)d_out;

    char* ws = (char*)d_ws;
    size_t off = 0;
    auto alloc = [&](size_t bytes) -> void* {
        void* p = ws + off;
        off = (off + bytes + 255) & ~(size_t)255;
        return p;
    };
    uint16_t* Xb   = (uint16_t*)alloc((size_t)M_PAD * 512 * 2);
    uint16_t* Wt   = (uint16_t*)alloc((size_t)1024 * 512 * 2);
    uint16_t* F    = (uint16_t*)alloc((size_t)M_PAD * 1024 * 2);
    float* ELui    = (float*)alloc((size_t)N_NODES * 8 * 4);
    float* ERui    = (float*)alloc((size_t)N_NODES * 8 * 4);
    float* ELiu    = (float*)alloc((size_t)N_NODES * 8 * 4);
    float* ERiu    = (float*)alloc((size_t)N_NODES * 8 * 4);
    int* offs_i    = (int*)alloc((size_t)(I_NODES + 1) * 4);
    int* cur_i     = (int*)alloc((size_t)I_NODES * 4);
    int* offs_u    = (int*)alloc((size_t)(U_NODES + 1) * 4);
    int* cur_u     = (int*)alloc((size_t)U_NODES * 4);
    int* sorted_ui = (int*)alloc((size_t)E_EDGES * 4);
    int* sorted_iu = (int*)alloc((size_t)E_EDGES * 4);
    float* ex_ui   = (float*)alloc((size_t)E_EDGES * 8 * 4);
    float* ex_iu   = (float*)alloc((size_t)E_EDGES * 8 * 4);
    float* itemF   = (float*)alloc((size_t)I_NODES * 512 * 4);
    float* partial2= (float*)alloc((size_t)80 * 512 * 4);
    // zeroed region (contiguous): counts_i, counts_u
    char* zptr = ws + off;
    int*   counts_i = (int*)alloc((size_t)I_NODES * 4);
    int*   counts_u = (int*)alloc((size_t)U_NODES * 4);
    size_t zbytes = (size_t)((ws + off) - zptr);
    float* mean_vec = (float*)alloc(512 * 4);
    (void)ws_size; (void)in_sizes; (void)n_in; (void)out_size;

    hipMemsetAsync(zptr, 0, zbytes, stream);
    prep_w<<<2048, 256, 0, stream>>>(W_ui, W_iu, Wt);
    gather_cast<<<M_PAD * 128 / 256, 256, 0, stream>>>(u_gid, i_gid, user_emb, item_emb, Xb);
    gemm_bf16<<<(M_PAD / 128) * 8, 256, 0, stream>>>(Xb, Wt, al_ui, ar_ui, al_iu, ar_iu,
                                                     F, ELui, ERui, ELiu, ERiu);
    hist_kernel<<<(E_EDGES + 255) / 256, 256, 0, stream>>>(src_u, dst_i, counts_i, counts_u);
    scan_kernel<<<2, 1024, 0, stream>>>(counts_i, counts_u, offs_i, cur_i, offs_u, cur_u);
    scatter_kernel<<<(E_EDGES + 255) / 256, 256, 0, stream>>>(src_u, dst_i, cur_i, cur_u,
                                                              sorted_ui, sorted_iu,
                                                              ELui, ERui, ELiu, ERiu,
                                                              ex_ui, ex_iu);
    agg3_kernel<<<IBLK + UBLK, 256, 0, stream>>>(offs_i, sorted_ui, ex_ui,
                                                 offs_u, sorted_iu, ex_iu,
                                                 F, b_iu, out, itemF);
    item_reduce<<<40, 256, 0, stream>>>(itemF, partial2);
    meanvec_kernel<<<1, 512, 0, stream>>>(partial2, b_ui, mean_vec);
    bcast_kernel<<<U_NODES * 128 / 256, 256, 0, stream>>>(mean_vec, out);
}

// Round 4
// 775.928 us; speedup vs baseline: 1.1841x; 1.1342x over previous
//
#include <hip/hip_runtime.h>
#include <hip/hip_bf16.h>
#include <stdint.h>

#define U_NODES 50000
#define I_NODES 20000
#define N_NODES 70000
#define M_PAD   70016      // 547 * 128
#define E_EDGES 400000
#define HID     512

typedef __attribute__((ext_vector_type(8))) short short8;   // 8 bf16 (4 VGPRs)
typedef __attribute__((ext_vector_type(4))) float floatx4;  // MFMA C/D frag

static __device__ __forceinline__ uint16_t f2b(float f) {
    uint32_t x = __float_as_uint(f);
    x += 0x7fffu + ((x >> 16) & 1u);          // RNE
    return (uint16_t)(x >> 16);
}
static __device__ __forceinline__ float b2f(short u) {
    return __uint_as_float(((uint32_t)(uint16_t)u) << 16);
}

// ---------------- gather + cast embeddings to bf16 ----------------
__global__ void gather_cast(const int* __restrict__ u_gid, const int* __restrict__ i_gid,
                            const float* __restrict__ user_emb, const float* __restrict__ item_emb,
                            uint16_t* __restrict__ Xb)
{
    int t = blockIdx.x * 256 + threadIdx.x;   // over M_PAD*128 (4 elems each)
    int n = t >> 7;
    int j = (t & 127) << 2;
    uint2 o;
    if (n < N_NODES) {
        const float* src = (n < U_NODES) ? (user_emb + (size_t)u_gid[n] * HID)
                                         : (item_emb + (size_t)i_gid[n - U_NODES] * HID);
        float4 v = *(const float4*)(src + j);
        o.x = (uint32_t)f2b(v.x) | ((uint32_t)f2b(v.y) << 16);
        o.y = (uint32_t)f2b(v.z) | ((uint32_t)f2b(v.w) << 16);
    } else { o.x = 0u; o.y = 0u; }            // zero the pad rows
    *(uint2*)(Xb + (size_t)n * HID + j) = o;
}

// ---------------- W_ui|W_iu -> transposed bf16 (Wt[n][k]) ----------------
__global__ void prep_w(const float* __restrict__ Wui, const float* __restrict__ Wiu,
                       uint16_t* __restrict__ Wt)
{
    int t = blockIdx.x * 256 + threadIdx.x;   // 1024*512
    int n = t >> 9, k = t & 511;
    float v = (n < 512) ? Wui[k * 512 + n] : Wiu[k * 512 + (n - 512)];
    Wt[(size_t)n * 512 + k] = f2b(v);
}

// ---------------- bf16 GEMM: F[M_PAD,1024] = Xb[M_PAD,512] @ Wt^T ----------------
// BK=32, double-buffered LDS, 2-phase pipeline (stage t+1 before compute t),
// XOR swizzle slot^=(row>>1)&3 (conflict-free b128 reads, linear gload_lds dest),
// XCD-aware block swizzle, fused EL/ER epilogue, dead-half F stores skipped.
__global__ __launch_bounds__(256) void gemm_bf16(const uint16_t* __restrict__ Xb,
                                                 const uint16_t* __restrict__ Wt,
                                                 const float* __restrict__ al_ui, const float* __restrict__ ar_ui,
                                                 const float* __restrict__ al_iu, const float* __restrict__ ar_iu,
                                                 uint16_t* __restrict__ F,
                                                 float* __restrict__ ELui, float* __restrict__ ERui,
                                                 float* __restrict__ ELiu, float* __restrict__ ERiu)
{
    __shared__ __align__(16) uint16_t As[2][128 * 32];
    __shared__ __align__(16) uint16_t Bs[2][128 * 32];
    const int tid = threadIdx.x;
    const int wave = tid >> 6, lane = tid & 63;

    // XCD-aware swizzle: 8 sibling n-blocks of one m-block land on the same XCD.
    int bid = blockIdx.x;
    int x = bid & 7, ii = bid >> 3;
    int L = x * 547 + ii;                 // bijective: grid 4376 = 8*547
    const int m0 = (L >> 3) * 128;
    const int n0 = (L & 7) * 128;
    const int wm = (wave & 1) * 64;
    const int wn = (wave >> 1) * 64;

    // staging: tile 128x32 = 8 chunks of 1KB; wave stages 2 A-chunks + 2 B-chunks.
    const int rl2 = lane >> 2;
    const int sg = ((lane & 3) ^ ((lane >> 3) & 3)) * 8;   // shorts
    const int ca = wave * 2, cb = wave * 2 + 1;
    const uint16_t* gA0 = Xb + (size_t)(m0 + ca * 16 + rl2) * HID + sg;
    const uint16_t* gA1 = Xb + (size_t)(m0 + cb * 16 + rl2) * HID + sg;
    const uint16_t* gB0 = Wt + (size_t)(n0 + ca * 16 + rl2) * HID + sg;
    const uint16_t* gB1 = Wt + (size_t)(n0 + cb * 16 + rl2) * HID + sg;

    floatx4 zero = {0.f, 0.f, 0.f, 0.f};
    floatx4 acc[4][4];
    #pragma unroll
    for (int a = 0; a < 4; ++a)
        #pragma unroll
        for (int b = 0; b < 4; ++b) acc[a][b] = zero;

    const int r = lane & 15, quad = lane >> 4;
    const int slq8 = (quad ^ ((r >> 1) & 3)) * 8;   // swizzled 8-short slot for reads

#define STAGE(KO, BUF) do {                                                                         \
    __builtin_amdgcn_global_load_lds((const __attribute__((address_space(1))) void*)(gA0 + (KO)),   \
                                     (__attribute__((address_space(3))) void*)(&As[BUF][ca * 512]), 16, 0, 0); \
    __builtin_amdgcn_global_load_lds((const __attribute__((address_space(1))) void*)(gA1 + (KO)),   \
                                     (__attribute__((address_space(3))) void*)(&As[BUF][cb * 512]), 16, 0, 0); \
    __builtin_amdgcn_global_load_lds((const __attribute__((address_space(1))) void*)(gB0 + (KO)),   \
                                     (__attribute__((address_space(3))) void*)(&Bs[BUF][ca * 512]), 16, 0, 0); \
    __builtin_amdgcn_global_load_lds((const __attribute__((address_space(1))) void*)(gB1 + (KO)),   \
                                     (__attribute__((address_space(3))) void*)(&Bs[BUF][cb * 512]), 16, 0, 0); \
} while (0)

#define COMPUTE(BUF) do {                                                                           \
    short8 af[4], bf[4];                                                                            \
    _Pragma("unroll")                                                                               \
    for (int tm = 0; tm < 4; ++tm)                                                                  \
        af[tm] = *(const short8*)&As[BUF][(wm + tm * 16 + r) * 32 + slq8];                          \
    _Pragma("unroll")                                                                               \
    for (int tn = 0; tn < 4; ++tn)                                                                  \
        bf[tn] = *(const short8*)&Bs[BUF][(wn + tn * 16 + r) * 32 + slq8];                          \
    _Pragma("unroll")                                                                               \
    for (int tm = 0; tm < 4; ++tm)                                                                  \
        _Pragma("unroll")                                                                           \
        for (int tn = 0; tn < 4; ++tn)                                                              \
            acc[tm][tn] = __builtin_amdgcn_mfma_f32_16x16x32_bf16(af[tm], bf[tn], acc[tm][tn], 0, 0, 0); \
} while (0)

    // prologue: tile 0 -> buf 0
    STAGE(0, 0);
    __syncthreads();
    // 2-phase pipeline: stage t+1 into buf^1, compute tile t, one barrier/step.
    #pragma unroll
    for (int t = 0; t < 15; ++t) {
        const int bc = t & 1;
        STAGE((t + 1) * 32, bc ^ 1);
        COMPUTE(bc);
        __syncthreads();
    }
    COMPUTE(1);

#undef STAGE
#undef COMPUTE

    // ---- epilogue ----
    // agg3 reads only F[user][0:512] and F[item][512:1024]; EL only for src
    // side (ELui[user], ELiu[item]); ER only for dst side (ERui[item], ERiu[user]).
    const bool collo = (n0 < 512);
    const bool allU = (m0 + 128 <= U_NODES);
    const bool allI = (m0 >= U_NODES);
    const bool storeb = (allU && collo) || (allI && !collo) || (!allU && !allI);

    const int colh = n0 + wn;                 // multiple of 64 -> exactly one head
    const int h = (colh & 511) >> 6;
    const float* arv = collo ? ar_ui : ar_iu;
    float* ERp = collo ? ERui : ERiu;
    float ar4[4];
    #pragma unroll
    for (int tn = 0; tn < 4; ++tn) ar4[tn] = arv[h * 64 + tn * 16 + r];

    if (storeb) {
        const float* alv = collo ? al_ui : al_iu;
        float* ELp = collo ? ELui : ELiu;
        float al4[4];
        #pragma unroll
        for (int tn = 0; tn < 4; ++tn) al4[tn] = alv[h * 64 + tn * 16 + r];
        #pragma unroll
        for (int tm = 0; tm < 4; ++tm) {
            #pragma unroll
            for (int rr = 0; rr < 4; ++rr) {
                int row = m0 + wm + tm * 16 + quad * 4 + rr;
                float sl = 0.f, sr = 0.f;
                #pragma unroll
                for (int tn = 0; tn < 4; ++tn) {
                    sl += acc[tm][tn][rr] * al4[tn];
                    sr += acc[tm][tn][rr] * ar4[tn];
                }
                if (row < N_NODES && ((row < U_NODES) == collo)) {
                    #pragma unroll
                    for (int tn = 0; tn < 4; ++tn) {
                        int col = n0 + wn + tn * 16 + r;
                        F[(size_t)row * 1024 + col] = f2b(acc[tm][tn][rr]);
                    }
                }
                #pragma unroll
                for (int d = 1; d < 16; d <<= 1) {
                    sl += __shfl_xor(sl, d);
                    sr += __shfl_xor(sr, d);
                }
                if (r == 0 && row < N_NODES) {
                    ELp[row * 8 + h] = sl;
                    ERp[row * 8 + h] = sr;
                }
            }
        }
    } else {
        // wrong-half block: F stores dead, only ER needed (dst-side logits).
        #pragma unroll
        for (int tm = 0; tm < 4; ++tm) {
            #pragma unroll
            for (int rr = 0; rr < 4; ++rr) {
                int row = m0 + wm + tm * 16 + quad * 4 + rr;
                float sr = 0.f;
                #pragma unroll
                for (int tn = 0; tn < 4; ++tn) sr += acc[tm][tn][rr] * ar4[tn];
                #pragma unroll
                for (int d = 1; d < 16; d <<= 1) sr += __shfl_xor(sr, d);
                if (r == 0 && row < N_NODES) ERp[row * 8 + h] = sr;
            }
        }
    }
}

// ---------------- CSR build ----------------
__global__ void hist_kernel(const int* __restrict__ src_u, const int* __restrict__ dst_i,
                            int* __restrict__ counts_i, int* __restrict__ counts_u)
{
    int e = blockIdx.x * 256 + threadIdx.x;
    if (e >= E_EDGES) return;
    atomicAdd(&counts_i[dst_i[e]], 1);
    atomicAdd(&counts_u[src_u[e]], 1);
}

// -------- two-level parallel scan: 69 chunk-sums -> 1-block scan -> rescan --------
#define SCAN_CHUNK 1024
#define IBLKS ((I_NODES + SCAN_CHUNK - 1) / SCAN_CHUNK)   // 20
#define UBLKS ((U_NODES + SCAN_CHUNK - 1) / SCAN_CHUNK)   // 49

__global__ __launch_bounds__(256) void scan_level1(const int* __restrict__ counts_i,
                                                   const int* __restrict__ counts_u,
                                                   int* __restrict__ bsum)
{
    int b = blockIdx.x, t = threadIdx.x;
    const int* cnt; int n, base;
    if (b < IBLKS) { cnt = counts_i; n = I_NODES; base = b * SCAN_CHUNK; }
    else           { cnt = counts_u; n = U_NODES; base = (b - IBLKS) * SCAN_CHUNK; }
    int idx = base + t * 4;
    int s = 0;
    #pragma unroll
    for (int k = 0; k < 4; ++k) { int i = idx + k; if (i < n) s += cnt[i]; }
    __shared__ int ws[4];
    int lane = t & 63, w = t >> 6;
    int xv = s;
    #pragma unroll
    for (int d = 1; d < 64; d <<= 1) xv += __shfl_xor(xv, d);
    if (lane == 0) ws[w] = xv;
    __syncthreads();
    if (t == 0) bsum[b] = ws[0] + ws[1] + ws[2] + ws[3];
}

__global__ void scan_level2(const int* __restrict__ bsum, int* __restrict__ boff,
                            int* __restrict__ offs_i, int* __restrict__ offs_u)
{
    int t = threadIdx.x;           // 128 = 2 waves: wave0 -> I segment, wave1 -> U
    int w = t >> 6, lane = t & 63;
    if (w == 0) {
        int v = (lane < IBLKS) ? bsum[lane] : 0;
        int xv = v;
        #pragma unroll
        for (int d = 1; d < 64; d <<= 1) { int y = __shfl_up(xv, d, 64); if (lane >= d) xv += y; }
        if (lane < IBLKS) boff[lane] = xv - v;
        if (lane == IBLKS - 1) offs_i[I_NODES] = xv;
    } else {
        int v = (lane < UBLKS) ? bsum[IBLKS + lane] : 0;
        int xv = v;
        #pragma unroll
        for (int d = 1; d < 64; d <<= 1) { int y = __shfl_up(xv, d, 64); if (lane >= d) xv += y; }
        if (lane < UBLKS) boff[IBLKS + lane] = xv - v;
        if (lane == UBLKS - 1) offs_u[U_NODES] = xv;
    }
}

__global__ __launch_bounds__(256) void scan_level3(const int* __restrict__ counts_i,
                                                   const int* __restrict__ counts_u,
                                                   const int* __restrict__ boff,
                                                   int* __restrict__ offs_i, int* __restrict__ cur_i,
                                                   int* __restrict__ offs_u, int* __restrict__ cur_u)
{
    int b = blockIdx.x, t = threadIdx.x;
    const int* cnt; int n, base; int* offs; int* cur;
    if (b < IBLKS) { cnt = counts_i; n = I_NODES; base = b * SCAN_CHUNK; offs = offs_i; cur = cur_i; }
    else           { cnt = counts_u; n = U_NODES; base = (b - IBLKS) * SCAN_CHUNK; offs = offs_u; cur = cur_u; }
    int idx = base + t * 4;
    int v[4]; int s = 0;
    #pragma unroll
    for (int k = 0; k < 4; ++k) { int i = idx + k; v[k] = (i < n) ? cnt[i] : 0; s += v[k]; }
    __shared__ int ws[4];
    int lane = t & 63, w = t >> 6;
    int xv = s;
    #pragma unroll
    for (int d = 1; d < 64; d <<= 1) { int y = __shfl_up(xv, d, 64); if (lane >= d) xv += y; }
    if (lane == 63) ws[w] = xv;
    __syncthreads();
    int wexcl = 0;
    #pragma unroll
    for (int k = 0; k < 4; ++k) if (k < w) wexcl += ws[k];
    int excl = boff[b] + wexcl + (xv - s);
    #pragma unroll
    for (int k = 0; k < 4; ++k) {
        int i = idx + k;
        if (i < n) { offs[i] = excl; cur[i] = excl; }
        excl += v[k];
    }
}

// ---------------- scatter: pure CSR permutation (ex computed in agg3) ----------------
__global__ void scatter_kernel(const int* __restrict__ src_u, const int* __restrict__ dst_i,
                               int* __restrict__ cur_i, int* __restrict__ cur_u,
                               int* __restrict__ sorted_ui, int* __restrict__ sorted_iu)
{
    int e = blockIdx.x * 256 + threadIdx.x;
    if (e >= E_EDGES) return;
    int s = src_u[e], d = dst_i[e];
    int p = atomicAdd(&cur_i[d], 1);
    int q = atomicAdd(&cur_u[s], 1);
    sorted_ui[p] = s;                  // user node id (src for ui)
    sorted_iu[q] = U_NODES + d;        // item node id (src for iu)
}

// ---------------- unified per-destination softmax + aggregate (single pass) ----------------
// wave per dst; attention weight exp(leaky(el[src]+er[dst])) computed inline:
// er is wave-constant, el gathered per edge (tables are L2-resident, 2.2 MB).
#define IBLK ((I_NODES + 3) / 4)
#define UBLK ((U_NODES + 3) / 4)
__global__ __launch_bounds__(256) void agg3_kernel(
    const int* __restrict__ offs_i, const int* __restrict__ sorted_ui,
    const int* __restrict__ offs_u, const int* __restrict__ sorted_iu,
    const float* __restrict__ ELui, const float* __restrict__ ERui,
    const float* __restrict__ ELiu, const float* __restrict__ ERiu,
    const uint16_t* __restrict__ F, const float* __restrict__ b_iu,
    float* __restrict__ out, float* __restrict__ itemF)
{
    int bid = blockIdx.x;
    int w = threadIdx.x >> 6, lane = threadIdx.x & 63;
    bool item_mode = bid < IBLK;
    const int* offs; const int* srcs; const float* el_tab; const float* er_tab;
    int dst, colbase, n_dst, dstnode;
    if (item_mode) {
        offs = offs_i; srcs = sorted_ui; el_tab = ELui; er_tab = ERui;
        dst = bid * 4 + w; colbase = 0; n_dst = I_NODES;
        dstnode = U_NODES + dst;
    } else {
        offs = offs_u; srcs = sorted_iu; el_tab = ELiu; er_tab = ERiu;
        dst = (bid - IBLK) * 4 + w; colbase = 512; n_dst = U_NODES;
        dstnode = dst;
    }
    if (dst >= n_dst) return;
    int h = lane >> 3;
    int j0 = offs[dst], j1 = offs[dst + 1];
    float er_h = er_tab[dstnode * 8 + h];

    float den = 0.f;
    float acc[8] = {0.f, 0.f, 0.f, 0.f, 0.f, 0.f, 0.f, 0.f};
    const int fb = colbase + lane * 8;
    int j = j0;
    for (; j + 8 <= j1; j += 8) {
        int s[8]; float wt[8]; short8 f[8];
        #pragma unroll
        for (int i = 0; i < 8; ++i) s[i] = srcs[j + i];
        #pragma unroll
        for (int i = 0; i < 8; ++i) {
            float e0 = el_tab[s[i] * 8 + h] + er_h;
            e0 = (e0 >= 0.f) ? e0 : 0.2f * e0;
            wt[i] = __expf(e0);
        }
        #pragma unroll
        for (int i = 0; i < 8; ++i) f[i] = *(const short8*)&F[(size_t)s[i] * 1024 + fb];
        #pragma unroll
        for (int i = 0; i < 8; ++i) {
            den += wt[i];
            #pragma unroll
            for (int q = 0; q < 8; ++q) acc[q] += wt[i] * b2f(f[i][q]);
        }
    }
    for (; j + 4 <= j1; j += 4) {
        int s[4]; float wt[4]; short8 f[4];
        #pragma unroll
        for (int i = 0; i < 4; ++i) s[i] = srcs[j + i];
        #pragma unroll
        for (int i = 0; i < 4; ++i) {
            float e0 = el_tab[s[i] * 8 + h] + er_h;
            e0 = (e0 >= 0.f) ? e0 : 0.2f * e0;
            wt[i] = __expf(e0);
        }
        #pragma unroll
        for (int i = 0; i < 4; ++i) f[i] = *(const short8*)&F[(size_t)s[i] * 1024 + fb];
        #pragma unroll
        for (int i = 0; i < 4; ++i) {
            den += wt[i];
            #pragma unroll
            for (int q = 0; q < 8; ++q) acc[q] += wt[i] * b2f(f[i][q]);
        }
    }
    for (; j < j1; ++j) {
        int s0 = srcs[j];
        float e0 = el_tab[s0 * 8 + h] + er_h;
        e0 = (e0 >= 0.f) ? e0 : 0.2f * e0;
        float w0 = __expf(e0);
        short8 f0 = *(const short8*)&F[(size_t)s0 * 1024 + fb];
        den += w0;
        #pragma unroll
        for (int q = 0; q < 8; ++q) acc[q] += w0 * b2f(f0[q]);
    }
    float inv = (j1 > j0) ? (1.f / den) : 0.f;
    #pragma unroll
    for (int q = 0; q < 8; ++q) acc[q] *= inv;

    int col = lane * 8;
    if (item_mode) {
        float* o = itemF + (size_t)dst * 512 + col;       // bias folded in later
        float4 v0 = {acc[0], acc[1], acc[2], acc[3]};
        float4 v1 = {acc[4], acc[5], acc[6], acc[7]};
        *(float4*)(o + 0) = v0;
        *(float4*)(o + 4) = v1;
    } else {
        float* o = out + (size_t)dst * 1024 + col;
        float4 v0 = {acc[0] + b_iu[col + 0], acc[1] + b_iu[col + 1],
                     acc[2] + b_iu[col + 2], acc[3] + b_iu[col + 3]};
        float4 v1 = {acc[4] + b_iu[col + 4], acc[5] + b_iu[col + 5],
                     acc[6] + b_iu[col + 6], acc[7] + b_iu[col + 7]};
        *(float4*)(o + 0) = v0;
        *(float4*)(o + 4) = v1;
    }
}

// ---------------- item mean: tree reduce itemF[20000][512] ----------------
// 160 blocks x 125 rows; block writes 2 partial stripes (rows split by t>>7)
__global__ void item_reduce(const float* __restrict__ itemF, float* __restrict__ partial2)
{
    int b = blockIdx.x;             // 0..159
    int t = threadIdx.x;            // 256
    int cg = (t & 127) * 4;         // column group (float4)
    int rp = t >> 7;                // 0/1
    float4 s = {0.f, 0.f, 0.f, 0.f};
    int r0 = b * 125;
    for (int r = r0 + rp; r < r0 + 125; r += 2) {
        float4 v = *(const float4*)&itemF[(size_t)r * 512 + cg];
        s.x += v.x; s.y += v.y; s.z += v.z; s.w += v.w;
    }
    *(float4*)&partial2[(size_t)(b * 2 + rp) * 512 + cg] = s;
}

__global__ void meanvec_kernel(const float* __restrict__ partial2, const float* __restrict__ b_ui,
                               float* __restrict__ mean_vec)
{
    int c = threadIdx.x;   // 512
    float s = 0.f;
    for (int p = 0; p < 320; ++p) s += partial2[p * 512 + c];
    mean_vec[c] = s * (1.0f / (float)I_NODES) + b_ui[c];
}

__global__ void bcast_kernel(const float* __restrict__ mean_vec, float* __restrict__ out)
{
    int t = blockIdx.x * 256 + threadIdx.x;   // U*128
    int u = t >> 7, q = t & 127;
    float4 v = ((const float4*)mean_vec)[q];
    *(float4*)(out + (size_t)u * 1024 + 512 + q * 4) = v;
}

extern "C" void kernel_launch(void* const* d_in, const int* in_sizes, int n_in,
                              void* d_out, int out_size, void* d_ws, size_t ws_size,
                              hipStream_t stream)
{
    const int*   u_gid    = (const int*)d_in[0];
    const int*   i_gid    = (const int*)d_in[1];
    const int*   src_u    = (const int*)d_in[2];
    const int*   dst_i    = (const int*)d_in[3];
    const float* user_emb = (const float*)d_in[4];
    const float* item_emb = (const float*)d_in[5];
    const float* W_ui     = (const float*)d_in[6];
    const float* al_ui    = (const float*)d_in[7];
    const float* ar_ui    = (const float*)d_in[8];
    const float* b_ui     = (const float*)d_in[9];
    const float* W_iu     = (const float*)d_in[10];
    const float* al_iu    = (const float*)d_in[11];
    const float* ar_iu    = (const float*)d_in[12];
    const float* b_iu     = (const float*)d_in[13];
    float* out = (float*)d_out;

    char* ws = (char*)d_ws;
    size_t off = 0;
    auto alloc = [&](size_t bytes) -> void* {
        void* p = ws + off;
        off = (off + bytes + 255) & ~(size_t)255;
        return p;
    };
    uint16_t* Xb   = (uint16_t*)alloc((size_t)M_PAD * 512 * 2);
    uint16_t* Wt   = (uint16_t*)alloc((size_t)1024 * 512 * 2);
    uint16_t* F    = (uint16_t*)alloc((size_t)M_PAD * 1024 * 2);
    float* ELui    = (float*)alloc((size_t)N_NODES * 8 * 4);
    float* ERui    = (float*)alloc((size_t)N_NODES * 8 * 4);
    float* ELiu    = (float*)alloc((size_t)N_NODES * 8 * 4);
    float* ERiu    = (float*)alloc((size_t)N_NODES * 8 * 4);
    int* offs_i    = (int*)alloc((size_t)(I_NODES + 1) * 4);
    int* cur_i     = (int*)alloc((size_t)I_NODES * 4);
    int* offs_u    = (int*)alloc((size_t)(U_NODES + 1) * 4);
    int* cur_u     = (int*)alloc((size_t)U_NODES * 4);
    int* sorted_ui = (int*)alloc((size_t)E_EDGES * 4);
    int* sorted_iu = (int*)alloc((size_t)E_EDGES * 4);
    int* bsum      = (int*)alloc((size_t)(IBLKS + UBLKS) * 4);
    int* boff      = (int*)alloc((size_t)(IBLKS + UBLKS) * 4);
    float* itemF   = (float*)alloc((size_t)I_NODES * 512 * 4);
    float* partial2= (float*)alloc((size_t)320 * 512 * 4);
    // zeroed region (contiguous): counts_i, counts_u
    char* zptr = ws + off;
    int*   counts_i = (int*)alloc((size_t)I_NODES * 4);
    int*   counts_u = (int*)alloc((size_t)U_NODES * 4);
    size_t zbytes = (size_t)((ws + off) - zptr);
    float* mean_vec = (float*)alloc(512 * 4);
    (void)ws_size; (void)in_sizes; (void)n_in; (void)out_size;

    hipMemsetAsync(zptr, 0, zbytes, stream);
    prep_w<<<2048, 256, 0, stream>>>(W_ui, W_iu, Wt);
    gather_cast<<<M_PAD * 128 / 256, 256, 0, stream>>>(u_gid, i_gid, user_emb, item_emb, Xb);
    gemm_bf16<<<(M_PAD / 128) * 8, 256, 0, stream>>>(Xb, Wt, al_ui, ar_ui, al_iu, ar_iu,
                                                     F, ELui, ERui, ELiu, ERiu);
    hist_kernel<<<(E_EDGES + 255) / 256, 256, 0, stream>>>(src_u, dst_i, counts_i, counts_u);
    scan_level1<<<IBLKS + UBLKS, 256, 0, stream>>>(counts_i, counts_u, bsum);
    scan_level2<<<1, 128, 0, stream>>>(bsum, boff, offs_i, offs_u);
    scan_level3<<<IBLKS + UBLKS, 256, 0, stream>>>(counts_i, counts_u, boff,
                                                   offs_i, cur_i, offs_u, cur_u);
    scatter_kernel<<<(E_EDGES + 255) / 256, 256, 0, stream>>>(src_u, dst_i, cur_i, cur_u,
                                                              sorted_ui, sorted_iu);
    agg3_kernel<<<IBLK + UBLK, 256, 0, stream>>>(offs_i, sorted_ui, offs_u, sorted_iu,
                                                 ELui, ERui, ELiu, ERiu,
                                                 F, b_iu, out, itemF);
    item_reduce<<<160, 256, 0, stream>>>(itemF, partial2);
    meanvec_kernel<<<1, 512, 0, stream>>>(partial2, b_ui, mean_vec);
    bcast_kernel<<<U_NODES * 128 / 256, 256, 0, stream>>>(mean_vec, out);
}

// Round 6
// 756.876 us; speedup vs baseline: 1.2139x; 1.0252x over previous
//
#include <hip/hip_runtime.h>
#include <hip/hip_bf16.h>
#include <stdint.h>

#define U_NODES 50000
#define I_NODES 20000
#define N_NODES 70000
#define M_PAD   70016      // 547 * 128
#define E_EDGES 400000
#define HID     512

typedef __attribute__((ext_vector_type(8))) short short8;   // 8 bf16 (4 VGPRs)
typedef __attribute__((ext_vector_type(4))) float floatx4;  // MFMA C/D frag / NT stores

static __device__ __forceinline__ uint16_t f2b(float f) {
    uint32_t x = __float_as_uint(f);
    x += 0x7fffu + ((x >> 16) & 1u);          // RNE
    return (uint16_t)(x >> 16);
}
static __device__ __forceinline__ float b2f(short u) {
    return __uint_as_float(((uint32_t)(uint16_t)u) << 16);
}

// ---------------- gather + cast embeddings to bf16 ----------------
__global__ void gather_cast(const int* __restrict__ u_gid, const int* __restrict__ i_gid,
                            const float* __restrict__ user_emb, const float* __restrict__ item_emb,
                            uint16_t* __restrict__ Xb)
{
    int t = blockIdx.x * 256 + threadIdx.x;   // over M_PAD*128 (4 elems each)
    int n = t >> 7;
    int j = (t & 127) << 2;
    uint2 o;
    if (n < N_NODES) {
        const float* src = (n < U_NODES) ? (user_emb + (size_t)u_gid[n] * HID)
                                         : (item_emb + (size_t)i_gid[n - U_NODES] * HID);
        float4 v = *(const float4*)(src + j);
        o.x = (uint32_t)f2b(v.x) | ((uint32_t)f2b(v.y) << 16);
        o.y = (uint32_t)f2b(v.z) | ((uint32_t)f2b(v.w) << 16);
    } else { o.x = 0u; o.y = 0u; }            // zero the pad rows
    *(uint2*)(Xb + (size_t)n * HID + j) = o;
}

// ---------------- W_ui|W_iu -> transposed bf16 (Wt[n][k]) ----------------
__global__ void prep_w(const float* __restrict__ Wui, const float* __restrict__ Wiu,
                       uint16_t* __restrict__ Wt)
{
    int t = blockIdx.x * 256 + threadIdx.x;   // 1024*512
    int n = t >> 9, k = t & 511;
    float v = (n < 512) ? Wui[k * 512 + n] : Wiu[k * 512 + (n - 512)];
    Wt[(size_t)n * 512 + k] = f2b(v);
}

// ---------------- bf16 GEMM: F[M_PAD,1024] = Xb[M_PAD,512] @ Wt^T ----------------
// BK=32, TRIPLE-buffered LDS, counted-vmcnt pipeline (stage 2 tiles ahead,
// s_waitcnt vmcnt(4) + raw s_barrier per step -- no full drain), XOR swizzle,
// XCD-aware block swizzle, fused EL/ER epilogue, dead-half F stores skipped.
__global__ __launch_bounds__(256) void gemm_bf16(const uint16_t* __restrict__ Xb,
                                                 const uint16_t* __restrict__ Wt,
                                                 const float* __restrict__ al_ui, const float* __restrict__ ar_ui,
                                                 const float* __restrict__ al_iu, const float* __restrict__ ar_iu,
                                                 uint16_t* __restrict__ F,
                                                 float* __restrict__ ELui, float* __restrict__ ERui,
                                                 float* __restrict__ ELiu, float* __restrict__ ERiu)
{
    __shared__ __align__(16) uint16_t As[3][128 * 32];   // 24 KB
    __shared__ __align__(16) uint16_t Bs[3][128 * 32];   // 24 KB
    const int tid = threadIdx.x;
    const int wave = tid >> 6, lane = tid & 63;

    // XCD-aware swizzle: 8 sibling n-blocks of one m-block land on the same XCD.
    int bid = blockIdx.x;
    int x = bid & 7, ii = bid >> 3;
    int L = x * 547 + ii;                 // bijective: grid 4376 = 8*547
    const int m0 = (L >> 3) * 128;
    const int n0 = (L & 7) * 128;
    const int wm = (wave & 1) * 64;
    const int wn = (wave >> 1) * 64;

    // staging: tile 128x32 = 8 chunks of 1KB; wave stages 2 A-chunks + 2 B-chunks.
    const int rl2 = lane >> 2;
    const int sg = ((lane & 3) ^ ((lane >> 3) & 3)) * 8;   // shorts
    const int ca = wave * 2, cb = wave * 2 + 1;
    const uint16_t* gA0 = Xb + (size_t)(m0 + ca * 16 + rl2) * HID + sg;
    const uint16_t* gA1 = Xb + (size_t)(m0 + cb * 16 + rl2) * HID + sg;
    const uint16_t* gB0 = Wt + (size_t)(n0 + ca * 16 + rl2) * HID + sg;
    const uint16_t* gB1 = Wt + (size_t)(n0 + cb * 16 + rl2) * HID + sg;

    floatx4 zero = {0.f, 0.f, 0.f, 0.f};
    floatx4 acc[4][4];
    #pragma unroll
    for (int a = 0; a < 4; ++a)
        #pragma unroll
        for (int b = 0; b < 4; ++b) acc[a][b] = zero;

    const int r = lane & 15, quad = lane >> 4;
    const int slq8 = (quad ^ ((r >> 1) & 3)) * 8;   // swizzled 8-short slot for reads

#define STAGE(KO, BUF) do {                                                                         \
    __builtin_amdgcn_global_load_lds((const __attribute__((address_space(1))) void*)(gA0 + (KO)),   \
                                     (__attribute__((address_space(3))) void*)(&As[BUF][ca * 512]), 16, 0, 0); \
    __builtin_amdgcn_global_load_lds((const __attribute__((address_space(1))) void*)(gA1 + (KO)),   \
                                     (__attribute__((address_space(3))) void*)(&As[BUF][cb * 512]), 16, 0, 0); \
    __builtin_amdgcn_global_load_lds((const __attribute__((address_space(1))) void*)(gB0 + (KO)),   \
                                     (__attribute__((address_space(3))) void*)(&Bs[BUF][ca * 512]), 16, 0, 0); \
    __builtin_amdgcn_global_load_lds((const __attribute__((address_space(1))) void*)(gB1 + (KO)),   \
                                     (__attribute__((address_space(3))) void*)(&Bs[BUF][cb * 512]), 16, 0, 0); \
} while (0)

#define COMPUTE(BUF) do {                                                                           \
    short8 af[4], bf[4];                                                                            \
    _Pragma("unroll")                                                                               \
    for (int tm = 0; tm < 4; ++tm)                                                                  \
        af[tm] = *(const short8*)&As[BUF][(wm + tm * 16 + r) * 32 + slq8];                          \
    _Pragma("unroll")                                                                               \
    for (int tn = 0; tn < 4; ++tn)                                                                  \
        bf[tn] = *(const short8*)&Bs[BUF][(wn + tn * 16 + r) * 32 + slq8];                          \
    _Pragma("unroll")                                                                               \
    for (int tm = 0; tm < 4; ++tm)                                                                  \
        _Pragma("unroll")                                                                           \
        for (int tn = 0; tn < 4; ++tn)                                                              \
            acc[tm][tn] = __builtin_amdgcn_mfma_f32_16x16x32_bf16(af[tm], bf[tn], acc[tm][tn], 0, 0, 0); \
} while (0)

    // prologue: stage tiles 0,1 into bufs 0,1 (8 loads in flight)
    STAGE(0, 0);
    STAGE(32, 1);
    // steady state: wait own tile-t loads (vmcnt(4): <=4 outstanding -> tile t
    // retired), barrier (=> ALL waves' tile-t loads retired), stage tile t+2
    // into buf (t+2)%3 == (t-1)%3 (safe: all reads of t-1 done pre-barrier),
    // compute tile t. Loads for t+1/t+2 stay in flight across the barrier.
    #pragma unroll
    for (int t = 0; t < 15; ++t) {
        asm volatile("s_waitcnt vmcnt(4)");
        __builtin_amdgcn_sched_barrier(0);
        __builtin_amdgcn_s_barrier();
        __builtin_amdgcn_sched_barrier(0);
        if (t < 14) STAGE((t + 2) * 32, (t + 2) % 3);
        COMPUTE(t % 3);
    }
    asm volatile("s_waitcnt vmcnt(0)");
    __builtin_amdgcn_sched_barrier(0);
    __builtin_amdgcn_s_barrier();
    __builtin_amdgcn_sched_barrier(0);
    COMPUTE(0);    // tile 15 lives in buf 15%3 == 0

#undef STAGE
#undef COMPUTE

    // ---- epilogue ----
    // agg3 reads only F[user][0:512] and F[item][512:1024]; EL only for src
    // side (ELui[user], ELiu[item]); ER only for dst side (ERui[item], ERiu[user]).
    const bool collo = (n0 < 512);
    const bool allU = (m0 + 128 <= U_NODES);
    const bool allI = (m0 >= U_NODES);
    const bool storeb = (allU && collo) || (allI && !collo) || (!allU && !allI);

    const int colh = n0 + wn;                 // multiple of 64 -> exactly one head
    const int h = (colh & 511) >> 6;
    const float* arv = collo ? ar_ui : ar_iu;
    float* ERp = collo ? ERui : ERiu;
    float ar4[4];
    #pragma unroll
    for (int tn = 0; tn < 4; ++tn) ar4[tn] = arv[h * 64 + tn * 16 + r];

    if (storeb) {
        const float* alv = collo ? al_ui : al_iu;
        float* ELp = collo ? ELui : ELiu;
        float al4[4];
        #pragma unroll
        for (int tn = 0; tn < 4; ++tn) al4[tn] = alv[h * 64 + tn * 16 + r];
        #pragma unroll
        for (int tm = 0; tm < 4; ++tm) {
            #pragma unroll
            for (int rr = 0; rr < 4; ++rr) {
                int row = m0 + wm + tm * 16 + quad * 4 + rr;
                float sl = 0.f, sr = 0.f;
                #pragma unroll
                for (int tn = 0; tn < 4; ++tn) {
                    sl += acc[tm][tn][rr] * al4[tn];
                    sr += acc[tm][tn][rr] * ar4[tn];
                }
                if (row < N_NODES && ((row < U_NODES) == collo)) {
                    #pragma unroll
                    for (int tn = 0; tn < 4; ++tn) {
                        int col = n0 + wn + tn * 16 + r;
                        F[(size_t)row * 1024 + col] = f2b(acc[tm][tn][rr]);
                    }
                }
                #pragma unroll
                for (int d = 1; d < 16; d <<= 1) {
                    sl += __shfl_xor(sl, d);
                    sr += __shfl_xor(sr, d);
                }
                if (r == 0 && row < N_NODES) {
                    ELp[row * 8 + h] = sl;
                    ERp[row * 8 + h] = sr;
                }
            }
        }
    } else {
        // wrong-half block: F stores dead, only ER needed (dst-side logits).
        #pragma unroll
        for (int tm = 0; tm < 4; ++tm) {
            #pragma unroll
            for (int rr = 0; rr < 4; ++rr) {
                int row = m0 + wm + tm * 16 + quad * 4 + rr;
                float sr = 0.f;
                #pragma unroll
                for (int tn = 0; tn < 4; ++tn) sr += acc[tm][tn][rr] * ar4[tn];
                #pragma unroll
                for (int d = 1; d < 16; d <<= 1) sr += __shfl_xor(sr, d);
                if (r == 0 && row < N_NODES) ERp[row * 8 + h] = sr;
            }
        }
    }
}

// ---------------- CSR build ----------------
__global__ void hist_kernel(const int* __restrict__ src_u, const int* __restrict__ dst_i,
                            int* __restrict__ counts_i, int* __restrict__ counts_u)
{
    int e = blockIdx.x * 256 + threadIdx.x;
    if (e >= E_EDGES) return;
    atomicAdd(&counts_i[dst_i[e]], 1);
    atomicAdd(&counts_u[src_u[e]], 1);
}

// -------- two-level parallel scan: chunk sums -> per-block re-scan (self prefix) --------
#define SCAN_CHUNK 1024
#define IBLKS ((I_NODES + SCAN_CHUNK - 1) / SCAN_CHUNK)   // 20
#define UBLKS ((U_NODES + SCAN_CHUNK - 1) / SCAN_CHUNK)   // 49

__global__ __launch_bounds__(256) void scan_level1(const int* __restrict__ counts_i,
                                                   const int* __restrict__ counts_u,
                                                   int* __restrict__ bsum)
{
    int b = blockIdx.x, t = threadIdx.x;
    const int* cnt; int n, base;
    if (b < IBLKS) { cnt = counts_i; n = I_NODES; base = b * SCAN_CHUNK; }
    else           { cnt = counts_u; n = U_NODES; base = (b - IBLKS) * SCAN_CHUNK; }
    int idx = base + t * 4;
    int s = 0;
    #pragma unroll
    for (int k = 0; k < 4; ++k) { int i = idx + k; if (i < n) s += cnt[i]; }
    __shared__ int ws[4];
    int lane = t & 63, w = t >> 6;
    int xv = s;
    #pragma unroll
    for (int d = 1; d < 64; d <<= 1) xv += __shfl_xor(xv, d);
    if (lane == 0) ws[w] = xv;
    __syncthreads();
    if (t == 0) bsum[b] = ws[0] + ws[1] + ws[2] + ws[3];
}

// per-block: recompute own segment prefix from bsum (<=49 values, one wave),
// then scan the 1024-chunk and write offs/cur. Last block also writes offs[n].
__global__ __launch_bounds__(256) void scan_level3(const int* __restrict__ counts_i,
                                                   const int* __restrict__ counts_u,
                                                   const int* __restrict__ bsum,
                                                   int* __restrict__ offs_i, int* __restrict__ cur_i,
                                                   int* __restrict__ offs_u, int* __restrict__ cur_u)
{
    int b = blockIdx.x, t = threadIdx.x;
    const int* cnt; int n, base, segfirst, seglast; int* offs; int* cur;
    if (b < IBLKS) { cnt = counts_i; n = I_NODES; base = b * SCAN_CHUNK; segfirst = 0; seglast = IBLKS - 1; offs = offs_i; cur = cur_i; }
    else           { cnt = counts_u; n = U_NODES; base = (b - IBLKS) * SCAN_CHUNK; segfirst = IBLKS; seglast = IBLKS + UBLKS - 1; offs = offs_u; cur = cur_u; }
    int lane = t & 63, w = t >> 6;

    __shared__ int s_boff;
    __shared__ int ws[4];
    if (w == 0) {
        int i = segfirst + lane;
        int v = (i < b) ? bsum[i] : 0;           // exclusive prefix of this block's segment
        #pragma unroll
        for (int d = 1; d < 64; d <<= 1) v += __shfl_xor(v, d);
        if (lane == 0) s_boff = v;
    }

    int idx = base + t * 4;
    int v4[4]; int s = 0;
    #pragma unroll
    for (int k = 0; k < 4; ++k) { int i = idx + k; v4[k] = (i < n) ? cnt[i] : 0; s += v4[k]; }
    int xv = s;
    #pragma unroll
    for (int d = 1; d < 64; d <<= 1) { int y = __shfl_up(xv, d, 64); if (lane >= d) xv += y; }
    if (lane == 63) ws[w] = xv;
    __syncthreads();
    int wexcl = 0;
    #pragma unroll
    for (int k = 0; k < 4; ++k) if (k < w) wexcl += ws[k];
    int excl = s_boff + wexcl + (xv - s);
    #pragma unroll
    for (int k = 0; k < 4; ++k) {
        int i = idx + k;
        if (i < n) { offs[i] = excl; cur[i] = excl; }
        excl += v4[k];
    }
    if (t == 0 && b == seglast)
        offs[n] = s_boff + ws[0] + ws[1] + ws[2] + ws[3];
}

// ---------------- scatter: pure CSR permutation (ex computed in agg3) ----------------
__global__ void scatter_kernel(const int* __restrict__ src_u, const int* __restrict__ dst_i,
                               int* __restrict__ cur_i, int* __restrict__ cur_u,
                               int* __restrict__ sorted_ui, int* __restrict__ sorted_iu)
{
    int e = blockIdx.x * 256 + threadIdx.x;
    if (e >= E_EDGES) return;
    int s = src_u[e], d = dst_i[e];
    int p = atomicAdd(&cur_i[d], 1);
    int q = atomicAdd(&cur_u[s], 1);
    sorted_ui[p] = s;                  // user node id (src for ui)
    sorted_iu[q] = U_NODES + d;        // item node id (src for iu)
}

// ---------------- unified per-destination softmax + aggregate (single pass) ----------------
// wave per dst; attention weight exp(leaky(el[src]+er[dst])) computed inline.
// out/itemF stores are NON-TEMPORAL: keeps the ~70MB hot F set resident in L3.
#define IBLK ((I_NODES + 3) / 4)
#define UBLK ((U_NODES + 3) / 4)
__global__ __launch_bounds__(256) void agg3_kernel(
    const int* __restrict__ offs_i, const int* __restrict__ sorted_ui,
    const int* __restrict__ offs_u, const int* __restrict__ sorted_iu,
    const float* __restrict__ ELui, const float* __restrict__ ERui,
    const float* __restrict__ ELiu, const float* __restrict__ ERiu,
    const uint16_t* __restrict__ F, const float* __restrict__ b_iu,
    float* __restrict__ out, float* __restrict__ itemF)
{
    int bid = blockIdx.x;
    int w = threadIdx.x >> 6, lane = threadIdx.x & 63;
    bool item_mode = bid < IBLK;
    const int* offs; const int* srcs; const float* el_tab; const float* er_tab;
    int dst, colbase, n_dst, dstnode;
    if (item_mode) {
        offs = offs_i; srcs = sorted_ui; el_tab = ELui; er_tab = ERui;
        dst = bid * 4 + w; colbase = 0; n_dst = I_NODES;
        dstnode = U_NODES + dst;
    } else {
        offs = offs_u; srcs = sorted_iu; el_tab = ELiu; er_tab = ERiu;
        dst = (bid - IBLK) * 4 + w; colbase = 512; n_dst = U_NODES;
        dstnode = dst;
    }
    if (dst >= n_dst) return;
    int h = lane >> 3;
    int j0 = offs[dst], j1 = offs[dst + 1];
    float er_h = er_tab[dstnode * 8 + h];

    float den = 0.f;
    float acc[8] = {0.f, 0.f, 0.f, 0.f, 0.f, 0.f, 0.f, 0.f};
    const int fb = colbase + lane * 8;
    int j = j0;
    for (; j + 8 <= j1; j += 8) {
        int s[8]; float wt[8]; short8 f[8];
        #pragma unroll
        for (int i = 0; i < 8; ++i) s[i] = srcs[j + i];
        #pragma unroll
        for (int i = 0; i < 8; ++i) {
            float e0 = el_tab[s[i] * 8 + h] + er_h;
            e0 = (e0 >= 0.f) ? e0 : 0.2f * e0;
            wt[i] = __expf(e0);
        }
        #pragma unroll
        for (int i = 0; i < 8; ++i) f[i] = *(const short8*)&F[(size_t)s[i] * 1024 + fb];
        #pragma unroll
        for (int i = 0; i < 8; ++i) {
            den += wt[i];
            #pragma unroll
            for (int q = 0; q < 8; ++q) acc[q] += wt[i] * b2f(f[i][q]);
        }
    }
    for (; j + 4 <= j1; j += 4) {
        int s[4]; float wt[4]; short8 f[4];
        #pragma unroll
        for (int i = 0; i < 4; ++i) s[i] = srcs[j + i];
        #pragma unroll
        for (int i = 0; i < 4; ++i) {
            float e0 = el_tab[s[i] * 8 + h] + er_h;
            e0 = (e0 >= 0.f) ? e0 : 0.2f * e0;
            wt[i] = __expf(e0);
        }
        #pragma unroll
        for (int i = 0; i < 4; ++i) f[i] = *(const short8*)&F[(size_t)s[i] * 1024 + fb];
        #pragma unroll
        for (int i = 0; i < 4; ++i) {
            den += wt[i];
            #pragma unroll
            for (int q = 0; q < 8; ++q) acc[q] += wt[i] * b2f(f[i][q]);
        }
    }
    for (; j < j1; ++j) {
        int s0 = srcs[j];
        float e0 = el_tab[s0 * 8 + h] + er_h;
        e0 = (e0 >= 0.f) ? e0 : 0.2f * e0;
        float w0 = __expf(e0);
        short8 f0 = *(const short8*)&F[(size_t)s0 * 1024 + fb];
        den += w0;
        #pragma unroll
        for (int q = 0; q < 8; ++q) acc[q] += w0 * b2f(f0[q]);
    }
    float inv = (j1 > j0) ? (1.f / den) : 0.f;
    #pragma unroll
    for (int q = 0; q < 8; ++q) acc[q] *= inv;

    int col = lane * 8;
    if (item_mode) {
        float* o = itemF + (size_t)dst * 512 + col;       // bias folded in later
        floatx4 v0 = {acc[0], acc[1], acc[2], acc[3]};
        floatx4 v1 = {acc[4], acc[5], acc[6], acc[7]};
        __builtin_nontemporal_store(v0, (floatx4*)(o + 0));
        __builtin_nontemporal_store(v1, (floatx4*)(o + 4));
    } else {
        float* o = out + (size_t)dst * 1024 + col;
        floatx4 v0 = {acc[0] + b_iu[col + 0], acc[1] + b_iu[col + 1],
                      acc[2] + b_iu[col + 2], acc[3] + b_iu[col + 3]};
        floatx4 v1 = {acc[4] + b_iu[col + 4], acc[5] + b_iu[col + 5],
                      acc[6] + b_iu[col + 6], acc[7] + b_iu[col + 7]};
        __builtin_nontemporal_store(v0, (floatx4*)(o + 0));
        __builtin_nontemporal_store(v1, (floatx4*)(o + 4));
    }
}

// ---------------- item mean: tree reduce itemF[20000][512] ----------------
// 160 blocks x 125 rows; block writes 2 partial stripes (rows split by t>>7)
__global__ void item_reduce(const float* __restrict__ itemF, float* __restrict__ partial2)
{
    int b = blockIdx.x;             // 0..159
    int t = threadIdx.x;            // 256
    int cg = (t & 127) * 4;         // column group (float4)
    int rp = t >> 7;                // 0/1
    float4 s = {0.f, 0.f, 0.f, 0.f};
    int r0 = b * 125;
    for (int r = r0 + rp; r < r0 + 125; r += 2) {
        float4 v = *(const float4*)&itemF[(size_t)r * 512 + cg];
        s.x += v.x; s.y += v.y; s.z += v.z; s.w += v.w;
    }
    *(float4*)&partial2[(size_t)(b * 2 + rp) * 512 + cg] = s;
}

__global__ void meanvec_kernel(const float* __restrict__ partial2, const float* __restrict__ b_ui,
                               float* __restrict__ mean_vec)
{
    int c = threadIdx.x;   // 512
    float s = 0.f;
    for (int p = 0; p < 320; ++p) s += partial2[p * 512 + c];
    mean_vec[c] = s * (1.0f / (float)I_NODES) + b_ui[c];
}

__global__ void bcast_kernel(const float* __restrict__ mean_vec, float* __restrict__ out)
{
    int t = blockIdx.x * 256 + threadIdx.x;   // U*128
    int u = t >> 7, q = t & 127;
    floatx4 v = ((const floatx4*)mean_vec)[q];
    __builtin_nontemporal_store(v, (floatx4*)(out + (size_t)u * 1024 + 512 + q * 4));
}

extern "C" void kernel_launch(void* const* d_in, const int* in_sizes, int n_in,
                              void* d_out, int out_size, void* d_ws, size_t ws_size,
                              hipStream_t stream)
{
    const int*   u_gid    = (const int*)d_in[0];
    const int*   i_gid    = (const int*)d_in[1];
    const int*   src_u    = (const int*)d_in[2];
    const int*   dst_i    = (const int*)d_in[3];
    const float* user_emb = (const float*)d_in[4];
    const float* item_emb = (const float*)d_in[5];
    const float* W_ui     = (const float*)d_in[6];
    const float* al_ui    = (const float*)d_in[7];
    const float* ar_ui    = (const float*)d_in[8];
    const float* b_ui     = (const float*)d_in[9];
    const float* W_iu     = (const float*)d_in[10];
    const float* al_iu    = (const float*)d_in[11];
    const float* ar_iu    = (const float*)d_in[12];
    const float* b_iu     = (const float*)d_in[13];
    float* out = (float*)d_out;

    char* ws = (char*)d_ws;
    size_t off = 0;
    auto alloc = [&](size_t bytes) -> void* {
        void* p = ws + off;
        off = (off + bytes + 255) & ~(size_t)255;
        return p;
    };
    uint16_t* Xb   = (uint16_t*)alloc((size_t)M_PAD * 512 * 2);
    uint16_t* Wt   = (uint16_t*)alloc((size_t)1024 * 512 * 2);
    uint16_t* F    = (uint16_t*)alloc((size_t)M_PAD * 1024 * 2);
    float* ELui    = (float*)alloc((size_t)N_NODES * 8 * 4);
    float* ERui    = (float*)alloc((size_t)N_NODES * 8 * 4);
    float* ELiu    = (float*)alloc((size_t)N_NODES * 8 * 4);
    float* ERiu    = (float*)alloc((size_t)N_NODES * 8 * 4);
    int* offs_i    = (int*)alloc((size_t)(I_NODES + 1) * 4);
    int* cur_i     = (int*)alloc((size_t)I_NODES * 4);
    int* offs_u    = (int*)alloc((size_t)(U_NODES + 1) * 4);
    int* cur_u     = (int*)alloc((size_t)U_NODES * 4);
    int* sorted_ui = (int*)alloc((size_t)E_EDGES * 4);
    int* sorted_iu = (int*)alloc((size_t)E_EDGES * 4);
    int* bsum      = (int*)alloc((size_t)(IBLKS + UBLKS) * 4);
    float* itemF   = (float*)alloc((size_t)I_NODES * 512 * 4);
    float* partial2= (float*)alloc((size_t)320 * 512 * 4);
    // zeroed region (contiguous): counts_i, counts_u
    char* zptr = ws + off;
    int*   counts_i = (int*)alloc((size_t)I_NODES * 4);
    int*   counts_u = (int*)alloc((size_t)U_NODES * 4);
    size_t zbytes = (size_t)((ws + off) - zptr);
    float* mean_vec = (float*)alloc(512 * 4);
    (void)ws_size; (void)in_sizes; (void)n_in; (void)out_size;

    hipMemsetAsync(zptr, 0, zbytes, stream);
    prep_w<<<2048, 256, 0, stream>>>(W_ui, W_iu, Wt);
    gather_cast<<<M_PAD * 128 / 256, 256, 0, stream>>>(u_gid, i_gid, user_emb, item_emb, Xb);
    gemm_bf16<<<(M_PAD / 128) * 8, 256, 0, stream>>>(Xb, Wt, al_ui, ar_ui, al_iu, ar_iu,
                                                     F, ELui, ERui, ELiu, ERiu);
    hist_kernel<<<(E_EDGES + 255) / 256, 256, 0, stream>>>(src_u, dst_i, counts_i, counts_u);
    scan_level1<<<IBLKS + UBLKS, 256, 0, stream>>>(counts_i, counts_u, bsum);
    scan_level3<<<IBLKS + UBLKS, 256, 0, stream>>>(counts_i, counts_u, bsum,
                                                   offs_i, cur_i, offs_u, cur_u);
    scatter_kernel<<<(E_EDGES + 255) / 256, 256, 0, stream>>>(src_u, dst_i, cur_i, cur_u,
                                                              sorted_ui, sorted_iu);
    agg3_kernel<<<IBLK + UBLK, 256, 0, stream>>>(offs_i, sorted_ui, offs_u, sorted_iu,
                                                 ELui, ERui, ELiu, ERiu,
                                                 F, b_iu, out, itemF);
    item_reduce<<<160, 256, 0, stream>>>(itemF, partial2);
    meanvec_kernel<<<1, 512, 0, stream>>>(partial2, b_ui, mean_vec);
    bcast_kernel<<<U_NODES * 128 / 256, 256, 0, stream>>>(mean_vec, out);
}